// Round 5
// baseline (6147.947 us; speedup 1.0000x reference)
//
#include <hip/hip_runtime.h>
#include <math.h>

namespace {

constexpr int Bc = 4, Tc = 1024, Cch = 768, Hc = 12, Dc = 64, KSEL = 10;
constexpr size_t BTC    = (size_t)Bc * Tc * Cch;        // 3,145,728
constexpr size_t PROBSN = (size_t)Bc * Hc * Tc * Tc;    // 50,331,648

// ---------------------------------------------------------------------------
// K1: QKV projection.  f32 GEMM, M=4096, N=768, K=768.  Tile 64x128, BK=16.
// ---------------------------------------------------------------------------
__global__ __launch_bounds__(256) void qkv_gemm(
    const float* __restrict__ hid,
    const float* __restrict__ Wq, const float* __restrict__ bq,
    const float* __restrict__ Wk, const float* __restrict__ bk,
    const float* __restrict__ Wv, const float* __restrict__ bv,
    float* __restrict__ qkv)
{
  const int z = blockIdx.z;
  const float* __restrict__ W    = (z == 0) ? Wq : (z == 1) ? Wk : Wv;
  const float* __restrict__ bias = (z == 0) ? bq : (z == 1) ? bk : bv;
  float* __restrict__ out = qkv + (size_t)z * BTC;

  const int m0 = blockIdx.y * 64;
  const int n0 = blockIdx.x * 128;

  __shared__ float aT[16][68];
  __shared__ float bN[16][132];

  const int t  = threadIdx.x;
  const int tn = t & 15;
  const int tq = t >> 4;

  float acc[4][8];
  #pragma unroll
  for (int i = 0; i < 4; ++i)
    #pragma unroll
    for (int j = 0; j < 8; ++j) acc[i][j] = 0.f;

  for (int k0 = 0; k0 < Cch; k0 += 16) {
    __syncthreads();
    {
      const int r = t >> 2, c = t & 3;
      const float4 v = *(const float4*)&hid[(size_t)(m0 + r) * Cch + k0 + 4*c];
      aT[4*c + 0][r] = v.x; aT[4*c + 1][r] = v.y;
      aT[4*c + 2][r] = v.z; aT[4*c + 3][r] = v.w;
    }
    #pragma unroll
    for (int p = 0; p < 2; ++p) {
      const int id = t + 256*p;
      const int kk = id >> 5, nc = id & 31;
      const float4 v = *(const float4*)&W[(size_t)(k0 + kk) * Cch + n0 + 4*nc];
      *(float4*)&bN[kk][4*nc] = v;
    }
    __syncthreads();
    #pragma unroll
    for (int kk = 0; kk < 16; ++kk) {
      const float4 a  = *(const float4*)&aT[kk][4*tq];
      const float4 b0 = *(const float4*)&bN[kk][4*tn];
      const float4 b1 = *(const float4*)&bN[kk][64 + 4*tn];
      const float av[4] = {a.x, a.y, a.z, a.w};
      const float bw[8] = {b0.x, b0.y, b0.z, b0.w, b1.x, b1.y, b1.z, b1.w};
      #pragma unroll
      for (int qi = 0; qi < 4; ++qi)
        #pragma unroll
        for (int ni = 0; ni < 8; ++ni) acc[qi][ni] += av[qi] * bw[ni];
    }
  }

  const float4 bb0 = *(const float4*)&bias[n0 + 4*tn];
  const float4 bb1 = *(const float4*)&bias[n0 + 64 + 4*tn];
  const int h0 = n0 >> 6;
  #pragma unroll
  for (int qi = 0; qi < 4; ++qi) {
    const int m = m0 + 4*tq + qi;
    const int b = m >> 10, tt = m & 1023;
    float4 o0, o1;
    o0.x = acc[qi][0] + bb0.x; o0.y = acc[qi][1] + bb0.y;
    o0.z = acc[qi][2] + bb0.z; o0.w = acc[qi][3] + bb0.w;
    o1.x = acc[qi][4] + bb1.x; o1.y = acc[qi][5] + bb1.y;
    o1.z = acc[qi][6] + bb1.z; o1.w = acc[qi][7] + bb1.w;
    *(float4*)&out[(((size_t)(b*Hc + h0    ))*Tc + tt)*Dc + 4*tn] = o0;
    *(float4*)&out[(((size_t)(b*Hc + h0 + 1))*Tc + tt)*Dc + 4*tn] = o1;
  }
}

// ---------------------------------------------------------------------------
// Phase-3 row processor: softmax + UCB top-k + renorm + count + sparse PV.
// cnt STREAMED (re-read at write time from L2); peak live ~ s16+u16+pvv+kvv.
// ---------------------------------------------------------------------------
__device__ __forceinline__ void process_row(
    const float (&a)[16],
    const int lane, const bool do_ucb, const float lt,
    const size_t rb,
    const float* __restrict__ count_in,
    float* __restrict__ probs_out, float* __restrict__ count_out,
    const float* __restrict__ Vh,      // V base for this (b,h): [1024][64]
    float* __restrict__ ctx_ptr)       // &ctx[row][h*64 + lane]
{
  float s[16];
  #pragma unroll
  for (int w = 0; w < 16; ++w) s[w] = a[w] * 0.125f;   // /sqrt(64)

  float mx = -INFINITY;
  #pragma unroll
  for (int w = 0; w < 16; ++w) mx = fmaxf(mx, s[w]);
  #pragma unroll
  for (int off = 32; off > 0; off >>= 1) mx = fmaxf(mx, __shfl_xor(mx, off));

  float sum = 0.f;
  #pragma unroll
  for (int w = 0; w < 16; ++w) { s[w] = __expf(s[w] - mx); sum += s[w]; }
  #pragma unroll
  for (int off = 32; off > 0; off >>= 1) sum += __shfl_xor(sum, off);

  const float rsum = 1.0f / sum;
  #pragma unroll
  for (int w = 0; w < 16; ++w) s[w] = s[w] * rsum;     // att

  if (do_ucb) {
    float u[16];
    #pragma unroll
    for (int w = 0; w < 16; ++w) {
      const float c = count_in[rb + lane + 64*w];      // streamed, not kept
      u[w] = s[w] + sqrtf(lt / (c + 1e-8f));
    }

    float pvv[KSEL];
    int   kvv[KSEL];
    unsigned sel = 0u;
    #pragma unroll
    for (int r = 0; r < KSEL; ++r) {
      float bu = -INFINITY, bs = 0.f; int bk = 1 << 30;
      #pragma unroll
      for (int w = 0; w < 16; ++w) {
        if (!((sel >> w) & 1u)) {
          const int kk = lane + 64*w;
          if (u[w] > bu || (u[w] == bu && kk < bk)) {
            bu = u[w]; bs = s[w]; bk = kk;
          }
        }
      }
      #pragma unroll
      for (int off = 32; off > 0; off >>= 1) {
        const float ov = __shfl_xor(bu, off);
        const float os = __shfl_xor(bs, off);
        const int   ok = __shfl_xor(bk, off);
        if (ov > bu || (ov == bu && ok < bk)) { bu = ov; bs = os; bk = ok; }
      }
      if ((bk & 63) == lane) sel |= 1u << (bk >> 6);
      pvv[r] = bs; kvv[r] = bk;
    }
    // u dead from here on

    float denom = 1e-8f;
    #pragma unroll
    for (int r = 0; r < KSEL; ++r) denom += pvv[r];
    const float rden = 1.0f / denom;

    #pragma unroll
    for (int w = 0; w < 16; ++w) {
      const float c  = count_in[rb + lane + 64*w];     // L2-hot re-read
      const bool  sb = (sel >> w) & 1u;
      probs_out[rb + lane + 64*w] = sb ? (s[w] * rden) : 0.0f;
      count_out[rb + lane + 64*w] = c + (sb ? 1.0f : 0.0f);
    }

    // sparse PV: ctx[d=lane] = (sum_r pvv[r] * V[kvv[r]][d]) * rden
    float cd = 0.f;
    #pragma unroll
    for (int r = 0; r < KSEL; ++r)
      cd += pvv[r] * Vh[(size_t)kvv[r] * Dc + lane];
    *ctx_ptr = cd * rden;
  } else {
    #pragma unroll
    for (int w = 0; w < 16; ++w) {
      probs_out[rb + lane + 64*w] = s[w];
      count_out[rb + lane + 64*w] = count_in[rb + lane + 64*w];
    }
    // dense ctx handled by guarded pv_gemm fallback
  }
}

// ---------------------------------------------------------------------------
// K2: fused scores + softmax + UCB top-k + renorm + count + sparse PV.
// 256 threads (4 waves), 16 q-rows/block; wave wv owns rows 4wv..4wv+3; lane
// owns k = lane + 64*w16.  Chunk loop fully unrolled with four separately
// named acc arrays (all indices static).  No register prefetch; TLP hides
// global latency.  __launch_bounds__(256,2): VGPR ceiling 256.
// ---------------------------------------------------------------------------
__global__ __launch_bounds__(256, 2) void attn_ucb(
    const float* __restrict__ qkv,
    const float* __restrict__ count_in,
    const int*   __restrict__ counter_p,
    const int*   __restrict__ ucb_p,
    float* __restrict__ probs_out,
    float* __restrict__ count_out,
    float* __restrict__ ctx)
{
  const int bh = blockIdx.y;
  const int q0 = blockIdx.x * 16;
  const int b  = bh / Hc, h = bh % Hc;
  const float* __restrict__ Qm = qkv;
  const float* __restrict__ Km = qkv + BTC;
  const float* __restrict__ Vh = qkv + 2*BTC + (size_t)bh * Tc * Dc;

  __shared__ float kN[128][68];   // K chunk [k][d], padded
  __shared__ float qN[16][68];    // Q tile  [r][d]

  const int t    = threadIdx.x;
  const int lane = t & 63;
  const int wv   = t >> 6;        // wave 0..3, owns rows 4wv..4wv+3

  {   // stage Q tile 16x64: 256 float4, 1/thread
    const int dq = t & 15, r = t >> 4;
    const float4 v = *(const float4*)&Qm[((size_t)bh*Tc + q0 + r)*Dc + 4*dq];
    *(float4*)&qN[r][4*dq] = v;
  }

  const int    dc    = t & 15;
  const int    kr    = t >> 4;
  const size_t kbase = (size_t)bh * Tc * Dc;

  float acc0[16], acc1[16], acc2[16], acc3[16];
  #pragma unroll
  for (int w = 0; w < 16; ++w) {
    acc0[w] = 0.f; acc1[w] = 0.f; acc2[w] = 0.f; acc3[w] = 0.f;
  }

  #pragma unroll
  for (int j = 0; j < 8; ++j) {          // fully unrolled -> static acc idx
    __syncthreads();
    #pragma unroll
    for (int p = 0; p < 8; ++p) {        // stage 128x64: 8 float4/thread
      const int row = kr + 16*p;
      *(float4*)&kN[row][4*dc] =
          *(const float4*)&Km[kbase + (size_t)(128*j + row)*Dc + 4*dc];
    }
    __syncthreads();
    #pragma unroll
    for (int d4 = 0; d4 < 16; ++d4) {
      const float4 qa = *(const float4*)&qN[4*wv    ][4*d4];
      const float4 qb = *(const float4*)&qN[4*wv + 1][4*d4];
      const float4 qc = *(const float4*)&qN[4*wv + 2][4*d4];
      const float4 qd = *(const float4*)&qN[4*wv + 3][4*d4];
      #pragma unroll
      for (int c = 0; c < 2; ++c) {
        const float4 kv = *(const float4*)&kN[lane + 64*c][4*d4];
        acc0[2*j + c] += qa.x*kv.x + qa.y*kv.y + qa.z*kv.z + qa.w*kv.w;
        acc1[2*j + c] += qb.x*kv.x + qb.y*kv.y + qb.z*kv.z + qb.w*kv.w;
        acc2[2*j + c] += qc.x*kv.x + qc.y*kv.y + qc.z*kv.z + qc.w*kv.w;
        acc3[2*j + c] += qd.x*kv.x + qd.y*kv.y + qd.z*kv.z + qd.w*kv.w;
      }
    }
  }

  // ---- phase 3 ----
  const int  counter = counter_p[0];
  const int  ucbf    = ucb_p[0];
  const bool do_ucb  = (ucbf != 0) && (counter >= 1000);
  const float lt     = do_ucb ? logf((float)counter) : 0.f;

  const int row0 = q0 + 4*wv;

  const size_t rb0 = ((size_t)bh*Tc + row0    ) * Tc;
  const size_t rb1 = ((size_t)bh*Tc + row0 + 1) * Tc;
  const size_t rb2 = ((size_t)bh*Tc + row0 + 2) * Tc;
  const size_t rb3 = ((size_t)bh*Tc + row0 + 3) * Tc;

  float* ctx0 = &ctx[((size_t)b*Tc + row0    )*Cch + h*Dc + lane];
  float* ctx1 = &ctx[((size_t)b*Tc + row0 + 1)*Cch + h*Dc + lane];
  float* ctx2 = &ctx[((size_t)b*Tc + row0 + 2)*Cch + h*Dc + lane];
  float* ctx3 = &ctx[((size_t)b*Tc + row0 + 3)*Cch + h*Dc + lane];

  process_row(acc0, lane, do_ucb, lt, rb0, count_in,
              probs_out, count_out, Vh, ctx0);
  process_row(acc1, lane, do_ucb, lt, rb1, count_in,
              probs_out, count_out, Vh, ctx1);
  process_row(acc2, lane, do_ucb, lt, rb2, count_in,
              probs_out, count_out, Vh, ctx2);
  process_row(acc3, lane, do_ucb, lt, rb3, count_in,
              probs_out, count_out, Vh, ctx3);
}

// ---------------------------------------------------------------------------
// K3 (fallback only, non-UCB path): ctx = probs @ V per (b,h).
// ---------------------------------------------------------------------------
__global__ __launch_bounds__(256) void pv_gemm(
    const float* __restrict__ probs,
    const float* __restrict__ Vm,
    float* __restrict__ ctx,
    const int* __restrict__ counter_p,
    const int* __restrict__ ucb_p)
{
  if ((ucb_p[0] != 0) && (counter_p[0] >= 1000)) return;  // K2 did sparse PV

  const int bh = blockIdx.y;
  const int q0 = blockIdx.x * 64;
  const int b = bh / Hc, h = bh % Hc;

  __shared__ float aT[32][68];
  __shared__ float vN[32][68];

  const int t  = threadIdx.x;
  const int tn = t & 15;
  const int tq = t >> 4;

  float acc[4][4];
  #pragma unroll
  for (int i = 0; i < 4; ++i)
    #pragma unroll
    for (int j = 0; j < 4; ++j) acc[i][j] = 0.f;

  for (int k0 = 0; k0 < Tc; k0 += 32) {
    __syncthreads();
    #pragma unroll
    for (int p = 0; p < 2; ++p) {
      const int id = t + 256*p;
      const int r = id >> 3, c = id & 7;
      const float4 v =
          *(const float4*)&probs[((size_t)bh*Tc + q0 + r)*Tc + k0 + 4*c];
      aT[4*c + 0][r] = v.x; aT[4*c + 1][r] = v.y;
      aT[4*c + 2][r] = v.z; aT[4*c + 3][r] = v.w;
    }
    #pragma unroll
    for (int p = 0; p < 2; ++p) {
      const int id = t + 256*p;
      const int kk = id >> 4, dcc = id & 15;
      const float4 v = *(const float4*)&Vm[((size_t)bh*Tc + k0 + kk)*Dc + 4*dcc];
      *(float4*)&vN[kk][4*dcc] = v;
    }
    __syncthreads();
    #pragma unroll
    for (int kk = 0; kk < 32; ++kk) {
      const float4 a  = *(const float4*)&aT[kk][4*tq];
      const float4 vv = *(const float4*)&vN[kk][4*tn];
      const float av[4] = {a.x, a.y, a.z, a.w};
      const float bw[4] = {vv.x, vv.y, vv.z, vv.w};
      #pragma unroll
      for (int qi = 0; qi < 4; ++qi)
        #pragma unroll
        for (int ni = 0; ni < 4; ++ni) acc[qi][ni] += av[qi] * bw[ni];
    }
  }

  #pragma unroll
  for (int qi = 0; qi < 4; ++qi) {
    const int tt = q0 + 4*tq + qi;
    float4 o;
    o.x = acc[qi][0]; o.y = acc[qi][1]; o.z = acc[qi][2]; o.w = acc[qi][3];
    *(float4*)&ctx[((size_t)b*Tc + tt)*Cch + h*Dc + 4*tn] = o;
  }
}

// ---------------------------------------------------------------------------
// K4: out = ctx @ Wo + bo.
// ---------------------------------------------------------------------------
__global__ __launch_bounds__(256) void out_gemm(
    const float* __restrict__ A,
    const float* __restrict__ W,
    const float* __restrict__ bias,
    float* __restrict__ out)
{
  const int m0 = blockIdx.y * 64;
  const int n0 = blockIdx.x * 128;

  __shared__ float aT[16][68];
  __shared__ float bN[16][132];

  const int t  = threadIdx.x;
  const int tn = t & 15;
  const int tq = t >> 4;

  float acc[4][8];
  #pragma unroll
  for (int i = 0; i < 4; ++i)
    #pragma unroll
    for (int j = 0; j < 8; ++j) acc[i][j] = 0.f;

  for (int k0 = 0; k0 < Cch; k0 += 16) {
    __syncthreads();
    {
      const int r = t >> 2, c = t & 3;
      const float4 v = *(const float4*)&A[(size_t)(m0 + r) * Cch + k0 + 4*c];
      aT[4*c + 0][r] = v.x; aT[4*c + 1][r] = v.y;
      aT[4*c + 2][r] = v.z; aT[4*c + 3][r] = v.w;
    }
    #pragma unroll
    for (int p = 0; p < 2; ++p) {
      const int id = t + 256*p;
      const int kk = id >> 5, nc = id & 31;
      const float4 v = *(const float4*)&W[(size_t)(k0 + kk) * Cch + n0 + 4*nc];
      *(float4*)&bN[kk][4*nc] = v;
    }
    __syncthreads();
    #pragma unroll
    for (int kk = 0; kk < 16; ++kk) {
      const float4 a  = *(const float4*)&aT[kk][4*tq];
      const float4 b0 = *(const float4*)&bN[kk][4*tn];
      const float4 b1 = *(const float4*)&bN[kk][64 + 4*tn];
      const float av[4] = {a.x, a.y, a.z, a.w};
      const float bw[8] = {b0.x, b0.y, b0.z, b0.w, b1.x, b1.y, b1.z, b1.w};
      #pragma unroll
      for (int qi = 0; qi < 4; ++qi)
        #pragma unroll
        for (int ni = 0; ni < 8; ++ni) acc[qi][ni] += av[qi] * bw[ni];
    }
  }

  const float4 bb0 = *(const float4*)&bias[n0 + 4*tn];
  const float4 bb1 = *(const float4*)&bias[n0 + 64 + 4*tn];
  #pragma unroll
  for (int qi = 0; qi < 4; ++qi) {
    const int m = m0 + 4*tq + qi;
    float4 o0, o1;
    o0.x = acc[qi][0] + bb0.x; o0.y = acc[qi][1] + bb0.y;
    o0.z = acc[qi][2] + bb0.z; o0.w = acc[qi][3] + bb0.w;
    o1.x = acc[qi][4] + bb1.x; o1.y = acc[qi][5] + bb1.y;
    o1.z = acc[qi][6] + bb1.z; o1.w = acc[qi][7] + bb1.w;
    *(float4*)&out[(size_t)m * Cch + n0 + 4*tn]      = o0;
    *(float4*)&out[(size_t)m * Cch + n0 + 64 + 4*tn] = o1;
  }
}

} // anonymous namespace

// ---------------------------------------------------------------------------
extern "C" void kernel_launch(void* const* d_in, const int* in_sizes, int n_in,
                              void* d_out, int out_size, void* d_ws, size_t ws_size,
                              hipStream_t stream) {
  (void)in_sizes; (void)n_in; (void)out_size; (void)ws_size;

  const float* hid  = (const float*)d_in[0];
  const float* cnt  = (const float*)d_in[1];
  const float* Wq   = (const float*)d_in[2];
  const float* bq   = (const float*)d_in[3];
  const float* Wk   = (const float*)d_in[4];
  const float* bk   = (const float*)d_in[5];
  const float* Wv   = (const float*)d_in[6];
  const float* bv   = (const float*)d_in[7];
  const float* Wo   = (const float*)d_in[8];
  const float* bo   = (const float*)d_in[9];
  const int* counter = (const int*)d_in[10];
  const int* ucb     = (const int*)d_in[11];

  float* out       = (float*)d_out;          // [B,T,C]
  float* probs     = out + BTC;              // [B,H,T,T]
  float* count_out = probs + PROBSN;         // [B,H,T,T]

  // workspace: Q | K | V | ctx, each BTC floats (needs 50.3 MB)
  float* ws  = (float*)d_ws;
  float* ctx = ws + 3*BTC;

  qkv_gemm<<<dim3(Cch/128, (Bc*Tc)/64, 3), 256, 0, stream>>>(
      hid, Wq, bq, Wk, bk, Wv, bv, ws);

  attn_ucb<<<dim3(Tc/16, Bc*Hc), 256, 0, stream>>>(
      ws, cnt, counter, ucb, probs, count_out, ctx);

  pv_gemm<<<dim3(Tc/64, Bc*Hc), 256, 0, stream>>>(
      probs, ws + 2*BTC, ctx, counter, ucb);

  out_gemm<<<dim3(Cch/128, (Bc*Tc)/64), 256, 0, stream>>>(
      ctx, Wo, bo, out);
}

// Round 6
// 676.305 us; speedup vs baseline: 9.0905x; 9.0905x over previous
//
#include <hip/hip_runtime.h>
#include <math.h>

namespace {

constexpr int Bc = 4, Tc = 1024, Cch = 768, Hc = 12, Dc = 64, KSEL = 10;
constexpr size_t BTC    = (size_t)Bc * Tc * Cch;        // 3,145,728
constexpr size_t PROBSN = (size_t)Bc * Hc * Tc * Tc;    // 50,331,648

// ---------------------------------------------------------------------------
// K1: QKV projection.  f32 GEMM, M=4096, N=768, K=768.  Tile 64x128, BK=16.
// ---------------------------------------------------------------------------
__global__ __launch_bounds__(256) void qkv_gemm(
    const float* __restrict__ hid,
    const float* __restrict__ Wq, const float* __restrict__ bq,
    const float* __restrict__ Wk, const float* __restrict__ bk,
    const float* __restrict__ Wv, const float* __restrict__ bv,
    float* __restrict__ qkv)
{
  const int z = blockIdx.z;
  const float* __restrict__ W    = (z == 0) ? Wq : (z == 1) ? Wk : Wv;
  const float* __restrict__ bias = (z == 0) ? bq : (z == 1) ? bk : bv;
  float* __restrict__ out = qkv + (size_t)z * BTC;

  const int m0 = blockIdx.y * 64;
  const int n0 = blockIdx.x * 128;

  __shared__ float aT[16][68];
  __shared__ float bN[16][132];

  const int t  = threadIdx.x;
  const int tn = t & 15;
  const int tq = t >> 4;

  float acc[4][8];
  #pragma unroll
  for (int i = 0; i < 4; ++i)
    #pragma unroll
    for (int j = 0; j < 8; ++j) acc[i][j] = 0.f;

  for (int k0 = 0; k0 < Cch; k0 += 16) {
    __syncthreads();
    {
      const int r = t >> 2, c = t & 3;
      const float4 v = *(const float4*)&hid[(size_t)(m0 + r) * Cch + k0 + 4*c];
      aT[4*c + 0][r] = v.x; aT[4*c + 1][r] = v.y;
      aT[4*c + 2][r] = v.z; aT[4*c + 3][r] = v.w;
    }
    #pragma unroll
    for (int p = 0; p < 2; ++p) {
      const int id = t + 256*p;
      const int kk = id >> 5, nc = id & 31;
      const float4 v = *(const float4*)&W[(size_t)(k0 + kk) * Cch + n0 + 4*nc];
      *(float4*)&bN[kk][4*nc] = v;
    }
    __syncthreads();
    #pragma unroll
    for (int kk = 0; kk < 16; ++kk) {
      const float4 a  = *(const float4*)&aT[kk][4*tq];
      const float4 b0 = *(const float4*)&bN[kk][4*tn];
      const float4 b1 = *(const float4*)&bN[kk][64 + 4*tn];
      const float av[4] = {a.x, a.y, a.z, a.w};
      const float bw[8] = {b0.x, b0.y, b0.z, b0.w, b1.x, b1.y, b1.z, b1.w};
      #pragma unroll
      for (int qi = 0; qi < 4; ++qi)
        #pragma unroll
        for (int ni = 0; ni < 8; ++ni) acc[qi][ni] += av[qi] * bw[ni];
    }
  }

  const float4 bb0 = *(const float4*)&bias[n0 + 4*tn];
  const float4 bb1 = *(const float4*)&bias[n0 + 64 + 4*tn];
  const int h0 = n0 >> 6;
  #pragma unroll
  for (int qi = 0; qi < 4; ++qi) {
    const int m = m0 + 4*tq + qi;
    const int b = m >> 10, tt = m & 1023;
    float4 o0, o1;
    o0.x = acc[qi][0] + bb0.x; o0.y = acc[qi][1] + bb0.y;
    o0.z = acc[qi][2] + bb0.z; o0.w = acc[qi][3] + bb0.w;
    o1.x = acc[qi][4] + bb1.x; o1.y = acc[qi][5] + bb1.y;
    o1.z = acc[qi][6] + bb1.z; o1.w = acc[qi][7] + bb1.w;
    *(float4*)&out[(((size_t)(b*Hc + h0    ))*Tc + tt)*Dc + 4*tn] = o0;
    *(float4*)&out[(((size_t)(b*Hc + h0 + 1))*Tc + tt)*Dc + 4*tn] = o1;
  }
}

// ---------------------------------------------------------------------------
// K2a: scores = 0.125 * Q @ K^T per (b,h).  Tile 64q x 128k, BK=64 (one-shot
// stage, no k-loop), 256 threads, 4x8/thread.  Writes into probs buffer.
// ---------------------------------------------------------------------------
__global__ __launch_bounds__(256) void score_gemm(
    const float* __restrict__ qkv,
    float* __restrict__ scores)
{
  const int k0 = blockIdx.x * 128;
  const int q0 = blockIdx.y * 64;
  const int bh = blockIdx.z;
  const float* __restrict__ Qm = qkv +          (size_t)bh * Tc * Dc;
  const float* __restrict__ Km = qkv + BTC +    (size_t)bh * Tc * Dc;

  __shared__ float qT[64][68];    // [d][q]
  __shared__ float kT[64][132];   // [d][k]

  const int t = threadIdx.x;

  #pragma unroll
  for (int p = 0; p < 4; ++p) {   // stage Q 64x64 transposed
    const int id = t + 256*p;
    const int r = id >> 4, c = id & 15;
    const float4 v = *(const float4*)&Qm[(size_t)(q0 + r) * Dc + 4*c];
    qT[4*c + 0][r] = v.x; qT[4*c + 1][r] = v.y;
    qT[4*c + 2][r] = v.z; qT[4*c + 3][r] = v.w;
  }
  #pragma unroll
  for (int p = 0; p < 8; ++p) {   // stage K 128x64 transposed
    const int id = t + 256*p;
    const int kk = id >> 4, c = id & 15;
    const float4 v = *(const float4*)&Km[(size_t)(k0 + kk) * Dc + 4*c];
    kT[4*c + 0][kk] = v.x; kT[4*c + 1][kk] = v.y;
    kT[4*c + 2][kk] = v.z; kT[4*c + 3][kk] = v.w;
  }
  __syncthreads();

  const int tn = t & 15;
  const int tq = t >> 4;

  float acc[4][8];
  #pragma unroll
  for (int i = 0; i < 4; ++i)
    #pragma unroll
    for (int j = 0; j < 8; ++j) acc[i][j] = 0.f;

  #pragma unroll 8
  for (int d = 0; d < 64; ++d) {
    const float4 a  = *(const float4*)&qT[d][4*tq];
    const float4 b0 = *(const float4*)&kT[d][4*tn];
    const float4 b1 = *(const float4*)&kT[d][64 + 4*tn];
    const float av[4] = {a.x, a.y, a.z, a.w};
    const float bw[8] = {b0.x, b0.y, b0.z, b0.w, b1.x, b1.y, b1.z, b1.w};
    #pragma unroll
    for (int qi = 0; qi < 4; ++qi)
      #pragma unroll
      for (int ni = 0; ni < 8; ++ni) acc[qi][ni] += av[qi] * bw[ni];
  }

  #pragma unroll
  for (int qi = 0; qi < 4; ++qi) {
    const int row = q0 + 4*tq + qi;
    const size_t base = ((size_t)bh * Tc + row) * Tc + k0;
    float4 o0, o1;
    o0.x = acc[qi][0] * 0.125f; o0.y = acc[qi][1] * 0.125f;
    o0.z = acc[qi][2] * 0.125f; o0.w = acc[qi][3] * 0.125f;
    o1.x = acc[qi][4] * 0.125f; o1.y = acc[qi][5] * 0.125f;
    o1.z = acc[qi][6] * 0.125f; o1.w = acc[qi][7] * 0.125f;
    *(float4*)&scores[base + 4*tn]      = o0;
    *(float4*)&scores[base + 64 + 4*tn] = o1;
  }
}

// ---------------------------------------------------------------------------
// K2b: streaming softmax + UCB top-k + renorm + count + sparse PV.
// One wave per q-row (4 waves/block).  Reads scaled scores from the probs
// buffer, overwrites it in place.  No GEMM -> phase-3 regs fit easily.
// ---------------------------------------------------------------------------
__global__ __launch_bounds__(256, 4) void ucb_topk(
    const float* __restrict__ qkv,
    const float* __restrict__ count_in,
    const int*   __restrict__ counter_p,
    const int*   __restrict__ ucb_p,
    float* __restrict__ probs,          // in: scaled scores; out: probs
    float* __restrict__ count_out,
    float* __restrict__ ctx)
{
  const int bh   = blockIdx.y;
  const int lane = threadIdx.x & 63;
  const int wv   = threadIdx.x >> 6;
  const int row  = blockIdx.x * 4 + wv;
  const int b = bh / Hc, h = bh % Hc;
  const size_t rb = ((size_t)bh * Tc + row) * Tc;
  const float* __restrict__ Vh = qkv + 2*BTC + (size_t)bh * Tc * Dc;

  const int  counter = counter_p[0];
  const int  ucbf    = ucb_p[0];
  const bool do_ucb  = (ucbf != 0) && (counter >= 1000);
  const float lt     = do_ucb ? logf((float)counter) : 0.f;

  float s[16], cnt[16];
  #pragma unroll
  for (int w = 0; w < 16; ++w) s[w]   = probs[rb + lane + 64*w];
  #pragma unroll
  for (int w = 0; w < 16; ++w) cnt[w] = count_in[rb + lane + 64*w];

  // softmax (scores already scaled by 0.125 in K2a)
  float mx = -INFINITY;
  #pragma unroll
  for (int w = 0; w < 16; ++w) mx = fmaxf(mx, s[w]);
  #pragma unroll
  for (int off = 32; off > 0; off >>= 1) mx = fmaxf(mx, __shfl_xor(mx, off));

  float sum = 0.f;
  #pragma unroll
  for (int w = 0; w < 16; ++w) { s[w] = __expf(s[w] - mx); sum += s[w]; }
  #pragma unroll
  for (int off = 32; off > 0; off >>= 1) sum += __shfl_xor(sum, off);

  const float rsum = 1.0f / sum;
  #pragma unroll
  for (int w = 0; w < 16; ++w) s[w] = s[w] * rsum;     // att

  if (do_ucb) {
    float u[16];
    #pragma unroll
    for (int w = 0; w < 16; ++w)
      u[w] = s[w] + sqrtf(lt / (cnt[w] + 1e-8f));

    float pvv[KSEL];
    int   kvv[KSEL];
    unsigned sel = 0u;
    #pragma unroll
    for (int r = 0; r < KSEL; ++r) {
      float bu = -INFINITY, bs = 0.f; int bk = 1 << 30;
      #pragma unroll
      for (int w = 0; w < 16; ++w) {
        if (!((sel >> w) & 1u)) {
          const int kk = lane + 64*w;
          if (u[w] > bu || (u[w] == bu && kk < bk)) {
            bu = u[w]; bs = s[w]; bk = kk;
          }
        }
      }
      #pragma unroll
      for (int off = 32; off > 0; off >>= 1) {
        const float ov = __shfl_xor(bu, off);
        const float os = __shfl_xor(bs, off);
        const int   ok = __shfl_xor(bk, off);
        if (ov > bu || (ov == bu && ok < bk)) { bu = ov; bs = os; bk = ok; }
      }
      if ((bk & 63) == lane) sel |= 1u << (bk >> 6);
      pvv[r] = bs; kvv[r] = bk;
    }

    float denom = 1e-8f;
    #pragma unroll
    for (int r = 0; r < KSEL; ++r) denom += pvv[r];
    const float rden = 1.0f / denom;

    #pragma unroll
    for (int w = 0; w < 16; ++w) {
      const bool sb = (sel >> w) & 1u;
      probs[rb + lane + 64*w]     = sb ? (s[w] * rden) : 0.0f;
      count_out[rb + lane + 64*w] = cnt[w] + (sb ? 1.0f : 0.0f);
    }

    // sparse PV: ctx[d=lane] = (sum_r pvv[r] * V[kvv[r]][d]) * rden
    float cd = 0.f;
    #pragma unroll
    for (int r = 0; r < KSEL; ++r)
      cd += pvv[r] * Vh[(size_t)kvv[r] * Dc + lane];
    ctx[((size_t)b*Tc + row)*Cch + h*Dc + lane] = cd * rden;
  } else {
    #pragma unroll
    for (int w = 0; w < 16; ++w) {
      probs[rb + lane + 64*w]     = s[w];
      count_out[rb + lane + 64*w] = cnt[w];
    }
    // dense ctx handled by guarded pv_gemm fallback
  }
}

// ---------------------------------------------------------------------------
// K3 (fallback only, non-UCB path): ctx = probs @ V per (b,h).
// ---------------------------------------------------------------------------
__global__ __launch_bounds__(256) void pv_gemm(
    const float* __restrict__ probs,
    const float* __restrict__ Vm,
    float* __restrict__ ctx,
    const int* __restrict__ counter_p,
    const int* __restrict__ ucb_p)
{
  if ((ucb_p[0] != 0) && (counter_p[0] >= 1000)) return;  // K2b did sparse PV

  const int bh = blockIdx.y;
  const int q0 = blockIdx.x * 64;
  const int b = bh / Hc, h = bh % Hc;

  __shared__ float aT[32][68];
  __shared__ float vN[32][68];

  const int t  = threadIdx.x;
  const int tn = t & 15;
  const int tq = t >> 4;

  float acc[4][4];
  #pragma unroll
  for (int i = 0; i < 4; ++i)
    #pragma unroll
    for (int j = 0; j < 4; ++j) acc[i][j] = 0.f;

  for (int k0 = 0; k0 < Tc; k0 += 32) {
    __syncthreads();
    #pragma unroll
    for (int p = 0; p < 2; ++p) {
      const int id = t + 256*p;
      const int r = id >> 3, c = id & 7;
      const float4 v =
          *(const float4*)&probs[((size_t)bh*Tc + q0 + r)*Tc + k0 + 4*c];
      aT[4*c + 0][r] = v.x; aT[4*c + 1][r] = v.y;
      aT[4*c + 2][r] = v.z; aT[4*c + 3][r] = v.w;
    }
    #pragma unroll
    for (int p = 0; p < 2; ++p) {
      const int id = t + 256*p;
      const int kk = id >> 4, dcc = id & 15;
      const float4 v = *(const float4*)&Vm[((size_t)bh*Tc + k0 + kk)*Dc + 4*dcc];
      *(float4*)&vN[kk][4*dcc] = v;
    }
    __syncthreads();
    #pragma unroll
    for (int kk = 0; kk < 32; ++kk) {
      const float4 a  = *(const float4*)&aT[kk][4*tq];
      const float4 vv = *(const float4*)&vN[kk][4*tn];
      const float av[4] = {a.x, a.y, a.z, a.w};
      const float bw[4] = {vv.x, vv.y, vv.z, vv.w};
      #pragma unroll
      for (int qi = 0; qi < 4; ++qi)
        #pragma unroll
        for (int ni = 0; ni < 4; ++ni) acc[qi][ni] += av[qi] * bw[ni];
    }
  }

  #pragma unroll
  for (int qi = 0; qi < 4; ++qi) {
    const int tt = q0 + 4*tq + qi;
    float4 o;
    o.x = acc[qi][0]; o.y = acc[qi][1]; o.z = acc[qi][2]; o.w = acc[qi][3];
    *(float4*)&ctx[((size_t)b*Tc + tt)*Cch + h*Dc + 4*tn] = o;
  }
}

// ---------------------------------------------------------------------------
// K4: out = ctx @ Wo + bo.
// ---------------------------------------------------------------------------
__global__ __launch_bounds__(256) void out_gemm(
    const float* __restrict__ A,
    const float* __restrict__ W,
    const float* __restrict__ bias,
    float* __restrict__ out)
{
  const int m0 = blockIdx.y * 64;
  const int n0 = blockIdx.x * 128;

  __shared__ float aT[16][68];
  __shared__ float bN[16][132];

  const int t  = threadIdx.x;
  const int tn = t & 15;
  const int tq = t >> 4;

  float acc[4][8];
  #pragma unroll
  for (int i = 0; i < 4; ++i)
    #pragma unroll
    for (int j = 0; j < 8; ++j) acc[i][j] = 0.f;

  for (int k0 = 0; k0 < Cch; k0 += 16) {
    __syncthreads();
    {
      const int r = t >> 2, c = t & 3;
      const float4 v = *(const float4*)&A[(size_t)(m0 + r) * Cch + k0 + 4*c];
      aT[4*c + 0][r] = v.x; aT[4*c + 1][r] = v.y;
      aT[4*c + 2][r] = v.z; aT[4*c + 3][r] = v.w;
    }
    #pragma unroll
    for (int p = 0; p < 2; ++p) {
      const int id = t + 256*p;
      const int kk = id >> 5, nc = id & 31;
      const float4 v = *(const float4*)&W[(size_t)(k0 + kk) * Cch + n0 + 4*nc];
      *(float4*)&bN[kk][4*nc] = v;
    }
    __syncthreads();
    #pragma unroll
    for (int kk = 0; kk < 16; ++kk) {
      const float4 a  = *(const float4*)&aT[kk][4*tq];
      const float4 b0 = *(const float4*)&bN[kk][4*tn];
      const float4 b1 = *(const float4*)&bN[kk][64 + 4*tn];
      const float av[4] = {a.x, a.y, a.z, a.w};
      const float bw[8] = {b0.x, b0.y, b0.z, b0.w, b1.x, b1.y, b1.z, b1.w};
      #pragma unroll
      for (int qi = 0; qi < 4; ++qi)
        #pragma unroll
        for (int ni = 0; ni < 8; ++ni) acc[qi][ni] += av[qi] * bw[ni];
    }
  }

  const float4 bb0 = *(const float4*)&bias[n0 + 4*tn];
  const float4 bb1 = *(const float4*)&bias[n0 + 64 + 4*tn];
  #pragma unroll
  for (int qi = 0; qi < 4; ++qi) {
    const int m = m0 + 4*tq + qi;
    float4 o0, o1;
    o0.x = acc[qi][0] + bb0.x; o0.y = acc[qi][1] + bb0.y;
    o0.z = acc[qi][2] + bb0.z; o0.w = acc[qi][3] + bb0.w;
    o1.x = acc[qi][4] + bb1.x; o1.y = acc[qi][5] + bb1.y;
    o1.z = acc[qi][6] + bb1.z; o1.w = acc[qi][7] + bb1.w;
    *(float4*)&out[(size_t)m * Cch + n0 + 4*tn]      = o0;
    *(float4*)&out[(size_t)m * Cch + n0 + 64 + 4*tn] = o1;
  }
}

} // anonymous namespace

// ---------------------------------------------------------------------------
extern "C" void kernel_launch(void* const* d_in, const int* in_sizes, int n_in,
                              void* d_out, int out_size, void* d_ws, size_t ws_size,
                              hipStream_t stream) {
  (void)in_sizes; (void)n_in; (void)out_size; (void)ws_size;

  const float* hid  = (const float*)d_in[0];
  const float* cnt  = (const float*)d_in[1];
  const float* Wq   = (const float*)d_in[2];
  const float* bq   = (const float*)d_in[3];
  const float* Wk   = (const float*)d_in[4];
  const float* bk   = (const float*)d_in[5];
  const float* Wv   = (const float*)d_in[6];
  const float* bv   = (const float*)d_in[7];
  const float* Wo   = (const float*)d_in[8];
  const float* bo   = (const float*)d_in[9];
  const int* counter = (const int*)d_in[10];
  const int* ucb     = (const int*)d_in[11];

  float* out       = (float*)d_out;          // [B,T,C]
  float* probs     = out + BTC;              // [B,H,T,T]  (scores, then probs)
  float* count_out = probs + PROBSN;         // [B,H,T,T]

  // workspace: Q | K | V | ctx, each BTC floats (needs 50.3 MB)
  float* ws  = (float*)d_ws;
  float* ctx = ws + 3*BTC;

  qkv_gemm<<<dim3(Cch/128, (Bc*Tc)/64, 3), 256, 0, stream>>>(
      hid, Wq, bq, Wk, bk, Wv, bv, ws);

  score_gemm<<<dim3(Tc/128, Tc/64, Bc*Hc), 256, 0, stream>>>(ws, probs);

  ucb_topk<<<dim3(Tc/4, Bc*Hc), 256, 0, stream>>>(
      ws, cnt, counter, ucb, probs, count_out, ctx);

  pv_gemm<<<dim3(Tc/64, Bc*Hc), 256, 0, stream>>>(
      probs, ws + 2*BTC, ctx, counter, ucb);

  out_gemm<<<dim3(Cch/128, (Bc*Tc)/64), 256, 0, stream>>>(
      ctx, Wo, bo, out);
}

// Round 7
// 624.106 us; speedup vs baseline: 9.8508x; 1.0836x over previous
//
#include <hip/hip_runtime.h>
#include <math.h>

namespace {

constexpr int Bc = 4, Tc = 1024, Cch = 768, Hc = 12, Dc = 64, KSEL = 10;
constexpr size_t BTC    = (size_t)Bc * Tc * Cch;        // 3,145,728
constexpr size_t PROBSN = (size_t)Bc * Hc * Tc * Tc;    // 50,331,648

typedef __attribute__((ext_vector_type(8))) short          bf16x8;
typedef __attribute__((ext_vector_type(4))) float          f32x4;
typedef __attribute__((ext_vector_type(4))) unsigned short u16x4;

// round-to-nearest-even f32 -> bf16 (raw bits); finite inputs only
__device__ __forceinline__ unsigned short bf16rne(float x) {
  unsigned int u = __float_as_uint(x);
  return (unsigned short)((u + 0x7FFFu + ((u >> 16) & 1u)) >> 16);
}
__device__ __forceinline__ float bf16tof(unsigned short h) {
  return __uint_as_float(((unsigned int)h) << 16);
}

// ---------------------------------------------------------------------------
// K1: QKV projection.  f32 GEMM, M=4096, N=768, K=768.  Tile 64x128, BK=16.
// ---------------------------------------------------------------------------
__global__ __launch_bounds__(256) void qkv_gemm(
    const float* __restrict__ hid,
    const float* __restrict__ Wq, const float* __restrict__ bq,
    const float* __restrict__ Wk, const float* __restrict__ bk,
    const float* __restrict__ Wv, const float* __restrict__ bv,
    float* __restrict__ qkv)
{
  const int z = blockIdx.z;
  const float* __restrict__ W    = (z == 0) ? Wq : (z == 1) ? Wk : Wv;
  const float* __restrict__ bias = (z == 0) ? bq : (z == 1) ? bk : bv;
  float* __restrict__ out = qkv + (size_t)z * BTC;

  const int m0 = blockIdx.y * 64;
  const int n0 = blockIdx.x * 128;

  __shared__ float aT[16][68];
  __shared__ float bN[16][132];

  const int t  = threadIdx.x;
  const int tn = t & 15;
  const int tq = t >> 4;

  float acc[4][8];
  #pragma unroll
  for (int i = 0; i < 4; ++i)
    #pragma unroll
    for (int j = 0; j < 8; ++j) acc[i][j] = 0.f;

  for (int k0 = 0; k0 < Cch; k0 += 16) {
    __syncthreads();
    {
      const int r = t >> 2, c = t & 3;
      const float4 v = *(const float4*)&hid[(size_t)(m0 + r) * Cch + k0 + 4*c];
      aT[4*c + 0][r] = v.x; aT[4*c + 1][r] = v.y;
      aT[4*c + 2][r] = v.z; aT[4*c + 3][r] = v.w;
    }
    #pragma unroll
    for (int p = 0; p < 2; ++p) {
      const int id = t + 256*p;
      const int kk = id >> 5, nc = id & 31;
      const float4 v = *(const float4*)&W[(size_t)(k0 + kk) * Cch + n0 + 4*nc];
      *(float4*)&bN[kk][4*nc] = v;
    }
    __syncthreads();
    #pragma unroll
    for (int kk = 0; kk < 16; ++kk) {
      const float4 a  = *(const float4*)&aT[kk][4*tq];
      const float4 b0 = *(const float4*)&bN[kk][4*tn];
      const float4 b1 = *(const float4*)&bN[kk][64 + 4*tn];
      const float av[4] = {a.x, a.y, a.z, a.w};
      const float bw[8] = {b0.x, b0.y, b0.z, b0.w, b1.x, b1.y, b1.z, b1.w};
      #pragma unroll
      for (int qi = 0; qi < 4; ++qi)
        #pragma unroll
        for (int ni = 0; ni < 8; ++ni) acc[qi][ni] += av[qi] * bw[ni];
    }
  }

  const float4 bb0 = *(const float4*)&bias[n0 + 4*tn];
  const float4 bb1 = *(const float4*)&bias[n0 + 64 + 4*tn];
  const int h0 = n0 >> 6;
  #pragma unroll
  for (int qi = 0; qi < 4; ++qi) {
    const int m = m0 + 4*tq + qi;
    const int b = m >> 10, tt = m & 1023;
    float4 o0, o1;
    o0.x = acc[qi][0] + bb0.x; o0.y = acc[qi][1] + bb0.y;
    o0.z = acc[qi][2] + bb0.z; o0.w = acc[qi][3] + bb0.w;
    o1.x = acc[qi][4] + bb1.x; o1.y = acc[qi][5] + bb1.y;
    o1.z = acc[qi][6] + bb1.z; o1.w = acc[qi][7] + bb1.w;
    *(float4*)&out[(((size_t)(b*Hc + h0    ))*Tc + tt)*Dc + 4*tn] = o0;
    *(float4*)&out[(((size_t)(b*Hc + h0 + 1))*Tc + tt)*Dc + 4*tn] = o1;
  }
}

// ---------------------------------------------------------------------------
// K2a: scores = 0.125 * Q @ K^T per (b,h), split-bf16 MFMA.
// Block 64q x 128k, 4 waves of 32q x 64k.  Q,K staged in LDS as bf16 hi/lo
// (3-term product: err ~2^-18).  One-shot stage (K=64), no k-loop.
// A/B frags share the (group,elem)->d convention so internal k-permutation
// cancels; C/D map col=lane&15, row=4*(lane>>4)+reg (HW-verified).
// ---------------------------------------------------------------------------
__global__ __launch_bounds__(256) void score_gemm(
    const float* __restrict__ qkv,
    float* __restrict__ scores)
{
  const int k0 = blockIdx.x * 128;
  const int q0 = blockIdx.y * 64;
  const int bh = blockIdx.z;
  const float* __restrict__ Qm = qkv +       (size_t)bh * Tc * Dc;
  const float* __restrict__ Km = qkv + BTC + (size_t)bh * Tc * Dc;

  __shared__ unsigned short Qh[64][72],  Ql[64][72];
  __shared__ unsigned short Kh[128][72], Kl[128][72];

  const int t = threadIdx.x;

  // stage Q 64x64 f32 -> bf16 hi/lo   (1024 float4, 4/thread)
  #pragma unroll
  for (int i = 0; i < 4; ++i) {
    const int idx = t + 256*i;
    const int r = idx >> 4, c4 = idx & 15;
    const float4 v = *(const float4*)&Qm[(size_t)(q0 + r) * Dc + 4*c4];
    const float xs[4] = {v.x, v.y, v.z, v.w};
    u16x4 hq, lq;
    #pragma unroll
    for (int e = 0; e < 4; ++e) {
      const unsigned short h = bf16rne(xs[e]);
      hq[e] = h;
      lq[e] = bf16rne(xs[e] - bf16tof(h));
    }
    *(u16x4*)&Qh[r][4*c4] = hq;
    *(u16x4*)&Ql[r][4*c4] = lq;
  }
  // stage K 128x64 f32 -> bf16 hi/lo  (2048 float4, 8/thread)
  #pragma unroll
  for (int i = 0; i < 8; ++i) {
    const int idx = t + 256*i;
    const int r = idx >> 4, c4 = idx & 15;
    const float4 v = *(const float4*)&Km[(size_t)(k0 + r) * Dc + 4*c4];
    const float xs[4] = {v.x, v.y, v.z, v.w};
    u16x4 hq, lq;
    #pragma unroll
    for (int e = 0; e < 4; ++e) {
      const unsigned short h = bf16rne(xs[e]);
      hq[e] = h;
      lq[e] = bf16rne(xs[e] - bf16tof(h));
    }
    *(u16x4*)&Kh[r][4*c4] = hq;
    *(u16x4*)&Kl[r][4*c4] = lq;
  }
  __syncthreads();

  const int lane = t & 63;
  const int wv   = t >> 6;          // wave 0..3
  const int wq   = (wv >> 1) * 32;  // wave q-offset: 0 / 32
  const int wk   = (wv & 1) * 64;   // wave k-offset: 0 / 64
  const int fr   = lane & 15;       // A row / B col within 16-tile
  const int fg   = lane >> 4;       // k-group 0..3

  f32x4 acc[2][4] = {};             // [qt][kt]

  #pragma unroll
  for (int g2 = 0; g2 < 2; ++g2) {  // d = 0..31 / 32..63
    const int dof = g2*32 + 8*fg;
    bf16x8 aH[2], aL[2];
    #pragma unroll
    for (int qt = 0; qt < 2; ++qt) {
      aH[qt] = *(const bf16x8*)&Qh[wq + qt*16 + fr][dof];
      aL[qt] = *(const bf16x8*)&Ql[wq + qt*16 + fr][dof];
    }
    #pragma unroll
    for (int kt = 0; kt < 4; ++kt) {
      const bf16x8 bH = *(const bf16x8*)&Kh[wk + kt*16 + fr][dof];
      const bf16x8 bL = *(const bf16x8*)&Kl[wk + kt*16 + fr][dof];
      #pragma unroll
      for (int qt = 0; qt < 2; ++qt) {
        acc[qt][kt] = __builtin_amdgcn_mfma_f32_16x16x32_bf16(
            aH[qt], bH, acc[qt][kt], 0, 0, 0);
        acc[qt][kt] = __builtin_amdgcn_mfma_f32_16x16x32_bf16(
            aH[qt], bL, acc[qt][kt], 0, 0, 0);
        acc[qt][kt] = __builtin_amdgcn_mfma_f32_16x16x32_bf16(
            aL[qt], bH, acc[qt][kt], 0, 0, 0);
      }
    }
  }

  // C write: row = 4*fg + j, col = fr  (verified C/D map), scale 0.125
  #pragma unroll
  for (int qt = 0; qt < 2; ++qt) {
    #pragma unroll
    for (int j = 0; j < 4; ++j) {
      const int qrow = q0 + wq + qt*16 + 4*fg + j;
      const size_t rb = ((size_t)bh * Tc + qrow) * Tc + k0 + wk;
      #pragma unroll
      for (int kt = 0; kt < 4; ++kt)
        scores[rb + kt*16 + fr] = acc[qt][kt][j] * 0.125f;
    }
  }
}

// ---------------------------------------------------------------------------
// K2b: streaming softmax + UCB top-k + renorm + count + sparse PV.
// One wave per q-row (4 waves/block).  Reads scaled scores from the probs
// buffer, overwrites it in place.  (unchanged from round 6)
// ---------------------------------------------------------------------------
__global__ __launch_bounds__(256, 4) void ucb_topk(
    const float* __restrict__ qkv,
    const float* __restrict__ count_in,
    const int*   __restrict__ counter_p,
    const int*   __restrict__ ucb_p,
    float* __restrict__ probs,          // in: scaled scores; out: probs
    float* __restrict__ count_out,
    float* __restrict__ ctx)
{
  const int bh   = blockIdx.y;
  const int lane = threadIdx.x & 63;
  const int wv   = threadIdx.x >> 6;
  const int row  = blockIdx.x * 4 + wv;
  const int b = bh / Hc, h = bh % Hc;
  const size_t rb = ((size_t)bh * Tc + row) * Tc;
  const float* __restrict__ Vh = qkv + 2*BTC + (size_t)bh * Tc * Dc;

  const int  counter = counter_p[0];
  const int  ucbf    = ucb_p[0];
  const bool do_ucb  = (ucbf != 0) && (counter >= 1000);
  const float lt     = do_ucb ? logf((float)counter) : 0.f;

  float s[16], cnt[16];
  #pragma unroll
  for (int w = 0; w < 16; ++w) s[w]   = probs[rb + lane + 64*w];
  #pragma unroll
  for (int w = 0; w < 16; ++w) cnt[w] = count_in[rb + lane + 64*w];

  // softmax (scores already scaled by 0.125 in K2a)
  float mx = -INFINITY;
  #pragma unroll
  for (int w = 0; w < 16; ++w) mx = fmaxf(mx, s[w]);
  #pragma unroll
  for (int off = 32; off > 0; off >>= 1) mx = fmaxf(mx, __shfl_xor(mx, off));

  float sum = 0.f;
  #pragma unroll
  for (int w = 0; w < 16; ++w) { s[w] = __expf(s[w] - mx); sum += s[w]; }
  #pragma unroll
  for (int off = 32; off > 0; off >>= 1) sum += __shfl_xor(sum, off);

  const float rsum = 1.0f / sum;
  #pragma unroll
  for (int w = 0; w < 16; ++w) s[w] = s[w] * rsum;     // att

  if (do_ucb) {
    float u[16];
    #pragma unroll
    for (int w = 0; w < 16; ++w)
      u[w] = s[w] + sqrtf(lt / (cnt[w] + 1e-8f));

    float pvv[KSEL];
    int   kvv[KSEL];
    unsigned sel = 0u;
    #pragma unroll
    for (int r = 0; r < KSEL; ++r) {
      float bu = -INFINITY, bs = 0.f; int bk = 1 << 30;
      #pragma unroll
      for (int w = 0; w < 16; ++w) {
        if (!((sel >> w) & 1u)) {
          const int kk = lane + 64*w;
          if (u[w] > bu || (u[w] == bu && kk < bk)) {
            bu = u[w]; bs = s[w]; bk = kk;
          }
        }
      }
      #pragma unroll
      for (int off = 32; off > 0; off >>= 1) {
        const float ov = __shfl_xor(bu, off);
        const float os = __shfl_xor(bs, off);
        const int   ok = __shfl_xor(bk, off);
        if (ov > bu || (ov == bu && ok < bk)) { bu = ov; bs = os; bk = ok; }
      }
      if ((bk & 63) == lane) sel |= 1u << (bk >> 6);
      pvv[r] = bs; kvv[r] = bk;
    }

    float denom = 1e-8f;
    #pragma unroll
    for (int r = 0; r < KSEL; ++r) denom += pvv[r];
    const float rden = 1.0f / denom;

    #pragma unroll
    for (int w = 0; w < 16; ++w) {
      const bool sb = (sel >> w) & 1u;
      probs[rb + lane + 64*w]     = sb ? (s[w] * rden) : 0.0f;
      count_out[rb + lane + 64*w] = cnt[w] + (sb ? 1.0f : 0.0f);
    }

    // sparse PV: ctx[d=lane] = (sum_r pvv[r] * V[kvv[r]][d]) * rden
    float cd = 0.f;
    #pragma unroll
    for (int r = 0; r < KSEL; ++r)
      cd += pvv[r] * Vh[(size_t)kvv[r] * Dc + lane];
    ctx[((size_t)b*Tc + row)*Cch + h*Dc + lane] = cd * rden;
  } else {
    #pragma unroll
    for (int w = 0; w < 16; ++w) {
      probs[rb + lane + 64*w]     = s[w];
      count_out[rb + lane + 64*w] = cnt[w];
    }
    // dense ctx handled by guarded pv_gemm fallback
  }
}

// ---------------------------------------------------------------------------
// K3 (fallback only, non-UCB path): ctx = probs @ V per (b,h).
// ---------------------------------------------------------------------------
__global__ __launch_bounds__(256) void pv_gemm(
    const float* __restrict__ probs,
    const float* __restrict__ Vm,
    float* __restrict__ ctx,
    const int* __restrict__ counter_p,
    const int* __restrict__ ucb_p)
{
  if ((ucb_p[0] != 0) && (counter_p[0] >= 1000)) return;  // K2b did sparse PV

  const int bh = blockIdx.y;
  const int q0 = blockIdx.x * 64;
  const int b = bh / Hc, h = bh % Hc;

  __shared__ float aT[32][68];
  __shared__ float vN[32][68];

  const int t  = threadIdx.x;
  const int tn = t & 15;
  const int tq = t >> 4;

  float acc[4][4];
  #pragma unroll
  for (int i = 0; i < 4; ++i)
    #pragma unroll
    for (int j = 0; j < 4; ++j) acc[i][j] = 0.f;

  for (int k0 = 0; k0 < Tc; k0 += 32) {
    __syncthreads();
    #pragma unroll
    for (int p = 0; p < 2; ++p) {
      const int id = t + 256*p;
      const int r = id >> 3, c = id & 7;
      const float4 v =
          *(const float4*)&probs[((size_t)bh*Tc + q0 + r)*Tc + k0 + 4*c];
      aT[4*c + 0][r] = v.x; aT[4*c + 1][r] = v.y;
      aT[4*c + 2][r] = v.z; aT[4*c + 3][r] = v.w;
    }
    #pragma unroll
    for (int p = 0; p < 2; ++p) {
      const int id = t + 256*p;
      const int kk = id >> 4, dcc = id & 15;
      const float4 v = *(const float4*)&Vm[((size_t)bh*Tc + k0 + kk)*Dc + 4*dcc];
      *(float4*)&vN[kk][4*dcc] = v;
    }
    __syncthreads();
    #pragma unroll
    for (int kk = 0; kk < 32; ++kk) {
      const float4 a  = *(const float4*)&aT[kk][4*tq];
      const float4 vv = *(const float4*)&vN[kk][4*tn];
      const float av[4] = {a.x, a.y, a.z, a.w};
      const float bw[4] = {vv.x, vv.y, vv.z, vv.w};
      #pragma unroll
      for (int qi = 0; qi < 4; ++qi)
        #pragma unroll
        for (int ni = 0; ni < 4; ++ni) acc[qi][ni] += av[qi] * bw[ni];
    }
  }

  #pragma unroll
  for (int qi = 0; qi < 4; ++qi) {
    const int tt = q0 + 4*tq + qi;
    float4 o;
    o.x = acc[qi][0]; o.y = acc[qi][1]; o.z = acc[qi][2]; o.w = acc[qi][3];
    *(float4*)&ctx[((size_t)b*Tc + tt)*Cch + h*Dc + 4*tn] = o;
  }
}

// ---------------------------------------------------------------------------
// K4: out = ctx @ Wo + bo.
// ---------------------------------------------------------------------------
__global__ __launch_bounds__(256) void out_gemm(
    const float* __restrict__ A,
    const float* __restrict__ W,
    const float* __restrict__ bias,
    float* __restrict__ out)
{
  const int m0 = blockIdx.y * 64;
  const int n0 = blockIdx.x * 128;

  __shared__ float aT[16][68];
  __shared__ float bN[16][132];

  const int t  = threadIdx.x;
  const int tn = t & 15;
  const int tq = t >> 4;

  float acc[4][8];
  #pragma unroll
  for (int i = 0; i < 4; ++i)
    #pragma unroll
    for (int j = 0; j < 8; ++j) acc[i][j] = 0.f;

  for (int k0 = 0; k0 < Cch; k0 += 16) {
    __syncthreads();
    {
      const int r = t >> 2, c = t & 3;
      const float4 v = *(const float4*)&A[(size_t)(m0 + r) * Cch + k0 + 4*c];
      aT[4*c + 0][r] = v.x; aT[4*c + 1][r] = v.y;
      aT[4*c + 2][r] = v.z; aT[4*c + 3][r] = v.w;
    }
    #pragma unroll
    for (int p = 0; p < 2; ++p) {
      const int id = t + 256*p;
      const int kk = id >> 5, nc = id & 31;
      const float4 v = *(const float4*)&W[(size_t)(k0 + kk) * Cch + n0 + 4*nc];
      *(float4*)&bN[kk][4*nc] = v;
    }
    __syncthreads();
    #pragma unroll
    for (int kk = 0; kk < 16; ++kk) {
      const float4 a  = *(const float4*)&aT[kk][4*tq];
      const float4 b0 = *(const float4*)&bN[kk][4*tn];
      const float4 b1 = *(const float4*)&bN[kk][64 + 4*tn];
      const float av[4] = {a.x, a.y, a.z, a.w};
      const float bw[8] = {b0.x, b0.y, b0.z, b0.w, b1.x, b1.y, b1.z, b1.w};
      #pragma unroll
      for (int qi = 0; qi < 4; ++qi)
        #pragma unroll
        for (int ni = 0; ni < 8; ++ni) acc[qi][ni] += av[qi] * bw[ni];
    }
  }

  const float4 bb0 = *(const float4*)&bias[n0 + 4*tn];
  const float4 bb1 = *(const float4*)&bias[n0 + 64 + 4*tn];
  #pragma unroll
  for (int qi = 0; qi < 4; ++qi) {
    const int m = m0 + 4*tq + qi;
    float4 o0, o1;
    o0.x = acc[qi][0] + bb0.x; o0.y = acc[qi][1] + bb0.y;
    o0.z = acc[qi][2] + bb0.z; o0.w = acc[qi][3] + bb0.w;
    o1.x = acc[qi][4] + bb1.x; o1.y = acc[qi][5] + bb1.y;
    o1.z = acc[qi][6] + bb1.z; o1.w = acc[qi][7] + bb1.w;
    *(float4*)&out[(size_t)m * Cch + n0 + 4*tn]      = o0;
    *(float4*)&out[(size_t)m * Cch + n0 + 64 + 4*tn] = o1;
  }
}

} // anonymous namespace

// ---------------------------------------------------------------------------
extern "C" void kernel_launch(void* const* d_in, const int* in_sizes, int n_in,
                              void* d_out, int out_size, void* d_ws, size_t ws_size,
                              hipStream_t stream) {
  (void)in_sizes; (void)n_in; (void)out_size; (void)ws_size;

  const float* hid  = (const float*)d_in[0];
  const float* cnt  = (const float*)d_in[1];
  const float* Wq   = (const float*)d_in[2];
  const float* bq   = (const float*)d_in[3];
  const float* Wk   = (const float*)d_in[4];
  const float* bk   = (const float*)d_in[5];
  const float* Wv   = (const float*)d_in[6];
  const float* bv   = (const float*)d_in[7];
  const float* Wo   = (const float*)d_in[8];
  const float* bo   = (const float*)d_in[9];
  const int* counter = (const int*)d_in[10];
  const int* ucb     = (const int*)d_in[11];

  float* out       = (float*)d_out;          // [B,T,C]
  float* probs     = out + BTC;              // [B,H,T,T]  (scores, then probs)
  float* count_out = probs + PROBSN;         // [B,H,T,T]

  // workspace: Q | K | V | ctx, each BTC floats (needs 50.3 MB)
  float* ws  = (float*)d_ws;
  float* ctx = ws + 3*BTC;

  qkv_gemm<<<dim3(Cch/128, (Bc*Tc)/64, 3), 256, 0, stream>>>(
      hid, Wq, bq, Wk, bk, Wv, bv, ws);

  score_gemm<<<dim3(Tc/128, Tc/64, Bc*Hc), 256, 0, stream>>>(ws, probs);

  ucb_topk<<<dim3(Tc/4, Bc*Hc), 256, 0, stream>>>(
      ws, cnt, counter, ucb, probs, count_out, ctx);

  pv_gemm<<<dim3(Tc/64, Bc*Hc), 256, 0, stream>>>(
      probs, ws + 2*BTC, ctx, counter, ucb);

  out_gemm<<<dim3(Cch/128, (Bc*Tc)/64), 256, 0, stream>>>(
      ctx, Wo, bo, out);
}

// Round 8
// 440.690 us; speedup vs baseline: 13.9507x; 1.4162x over previous
//
#include <hip/hip_runtime.h>
#include <math.h>

namespace {

constexpr int Bc = 4, Tc = 1024, Cch = 768, Hc = 12, Dc = 64, KSEL = 10;
constexpr size_t BTC    = (size_t)Bc * Tc * Cch;        // 3,145,728
constexpr size_t PROBSN = (size_t)Bc * Hc * Tc * Tc;    // 50,331,648
constexpr size_t CC     = (size_t)Cch * Cch;            // 589,824

typedef __attribute__((ext_vector_type(8))) short          bf16x8;
typedef __attribute__((ext_vector_type(4))) float          f32x4;
typedef __attribute__((ext_vector_type(4))) unsigned short u16x4;
typedef __attribute__((ext_vector_type(8))) unsigned short u16x8;

// round-to-nearest-even f32 -> bf16 (raw bits); finite inputs only
__device__ __forceinline__ unsigned short bf16rne(float x) {
  unsigned int u = __float_as_uint(x);
  return (unsigned short)((u + 0x7FFFu + ((u >> 16) & 1u)) >> 16);
}
__device__ __forceinline__ float bf16tof(unsigned short h) {
  return __uint_as_float(((unsigned int)h) << 16);
}

// ---------------------------------------------------------------------------
// split_plane: f32[n] -> bf16 hi/lo planes.  n multiple of 1024.
// ---------------------------------------------------------------------------
__global__ __launch_bounds__(256) void split_plane(
    const float* __restrict__ src,
    unsigned short* __restrict__ h, unsigned short* __restrict__ l)
{
  const size_t i = (size_t)(blockIdx.x * 256 + threadIdx.x) * 4;
  const float4 v = *(const float4*)&src[i];
  const float xs[4] = {v.x, v.y, v.z, v.w};
  u16x4 hh, ll;
  #pragma unroll
  for (int e = 0; e < 4; ++e) {
    const unsigned short hb = bf16rne(xs[e]);
    hh[e] = hb;
    ll[e] = bf16rne(xs[e] - bf16tof(hb));
  }
  *(u16x4*)&h[i] = hh;
  *(u16x4*)&l[i] = ll;
}

// ---------------------------------------------------------------------------
// splitT_w: W[k][n] (768x768 f32) -> transposed bf16 planes th/tl [n][k].
// 32x32 LDS tile transpose, coalesced both sides.
// ---------------------------------------------------------------------------
__global__ __launch_bounds__(256) void splitT_w(
    const float* __restrict__ W,
    unsigned short* __restrict__ th, unsigned short* __restrict__ tl)
{
  __shared__ float tile[32][33];
  const int n0 = blockIdx.x * 32, k0 = blockIdx.y * 32;
  const int x = threadIdx.x & 31, y = threadIdx.x >> 5;   // y 0..7

  #pragma unroll
  for (int i = 0; i < 4; ++i) {
    const int kk = y * 4 + i;
    tile[kk][x] = W[(size_t)(k0 + kk) * Cch + n0 + x];
  }
  __syncthreads();
  #pragma unroll
  for (int i = 0; i < 4; ++i) {
    const int nn = y * 4 + i;
    const float v = tile[x][nn];                          // = W[k0+x][n0+nn]
    const unsigned short hb = bf16rne(v);
    th[(size_t)(n0 + nn) * Cch + k0 + x] = hb;
    tl[(size_t)(n0 + nn) * Cch + k0 + x] = bf16rne(v - bf16tof(hb));
  }
}

// ---------------------------------------------------------------------------
// qkv_mfma: [Q|K|V] = hid @ W + b, split-bf16 MFMA.  A = hid planes [m][k],
// B = W^T planes [n][k].  Tile 64m x 128n, BK=64, 4 waves of 32m x 64n.
// z<2 writes bf16 hi/lo head-interleaved planes (score consumes directly);
// z==2 writes V as f32.
// ---------------------------------------------------------------------------
__global__ __launch_bounds__(256) void qkv_mfma(
    const unsigned short* __restrict__ hidh, const unsigned short* __restrict__ hidl,
    const unsigned short* __restrict__ wqth, const unsigned short* __restrict__ wqtl,
    const unsigned short* __restrict__ wkth, const unsigned short* __restrict__ wktl,
    const unsigned short* __restrict__ wvth, const unsigned short* __restrict__ wvtl,
    const float* __restrict__ bq, const float* __restrict__ bk,
    const float* __restrict__ bv,
    unsigned short* __restrict__ qh, unsigned short* __restrict__ ql,
    unsigned short* __restrict__ kh, unsigned short* __restrict__ kl,
    float* __restrict__ V)
{
  const int z = blockIdx.z;
  const unsigned short* __restrict__ Bhp = (z == 0) ? wqth : (z == 1) ? wkth : wvth;
  const unsigned short* __restrict__ Blp = (z == 0) ? wqtl : (z == 1) ? wktl : wvtl;
  const float* __restrict__ bias = (z == 0) ? bq : (z == 1) ? bk : bv;

  const int m0 = blockIdx.y * 64;
  const int n0 = blockIdx.x * 128;

  __shared__ unsigned short Ah[64][72],  Al[64][72];
  __shared__ unsigned short Bh[128][72], Bl[128][72];

  const int t    = threadIdx.x;
  const int lane = t & 63;
  const int wv   = t >> 6;
  const int wq   = (wv >> 1) * 32;
  const int wk   = (wv & 1) * 64;
  const int fr   = lane & 15;
  const int fg   = lane >> 4;

  f32x4 acc[2][4] = {};

  for (int k0 = 0; k0 < Cch; k0 += 64) {
    __syncthreads();
    #pragma unroll
    for (int i = 0; i < 2; ++i) {       // A: 64x64 x 2 planes
      const int id = t + 256*i;
      const int r = id >> 3, c8 = (id & 7) * 8;
      *(u16x8*)&Ah[r][c8] = *(const u16x8*)&hidh[(size_t)(m0 + r)*Cch + k0 + c8];
      *(u16x8*)&Al[r][c8] = *(const u16x8*)&hidl[(size_t)(m0 + r)*Cch + k0 + c8];
    }
    #pragma unroll
    for (int i = 0; i < 4; ++i) {       // B: 128x64 x 2 planes
      const int id = t + 256*i;
      const int r = id >> 3, c8 = (id & 7) * 8;
      *(u16x8*)&Bh[r][c8] = *(const u16x8*)&Bhp[(size_t)(n0 + r)*Cch + k0 + c8];
      *(u16x8*)&Bl[r][c8] = *(const u16x8*)&Blp[(size_t)(n0 + r)*Cch + k0 + c8];
    }
    __syncthreads();

    #pragma unroll
    for (int g2 = 0; g2 < 2; ++g2) {
      const int dof = g2*32 + 8*fg;
      bf16x8 aH[2], aL[2];
      #pragma unroll
      for (int qt = 0; qt < 2; ++qt) {
        aH[qt] = *(const bf16x8*)&Ah[wq + qt*16 + fr][dof];
        aL[qt] = *(const bf16x8*)&Al[wq + qt*16 + fr][dof];
      }
      #pragma unroll
      for (int kt = 0; kt < 4; ++kt) {
        const bf16x8 bH = *(const bf16x8*)&Bh[wk + kt*16 + fr][dof];
        const bf16x8 bL = *(const bf16x8*)&Bl[wk + kt*16 + fr][dof];
        #pragma unroll
        for (int qt = 0; qt < 2; ++qt) {
          acc[qt][kt] = __builtin_amdgcn_mfma_f32_16x16x32_bf16(
              aH[qt], bH, acc[qt][kt], 0, 0, 0);
          acc[qt][kt] = __builtin_amdgcn_mfma_f32_16x16x32_bf16(
              aH[qt], bL, acc[qt][kt], 0, 0, 0);
          acc[qt][kt] = __builtin_amdgcn_mfma_f32_16x16x32_bf16(
              aL[qt], bH, acc[qt][kt], 0, 0, 0);
        }
      }
    }
  }

  float bcol[4];
  #pragma unroll
  for (int kt = 0; kt < 4; ++kt) bcol[kt] = bias[n0 + wk + kt*16 + fr];

  unsigned short* __restrict__ dh = (z == 0) ? qh : kh;
  unsigned short* __restrict__ dl = (z == 0) ? ql : kl;

  #pragma unroll
  for (int qt = 0; qt < 2; ++qt) {
    #pragma unroll
    for (int j = 0; j < 4; ++j) {
      const int m  = m0 + wq + qt*16 + 4*fg + j;
      const int b  = m >> 10, tt = m & 1023;
      #pragma unroll
      for (int kt = 0; kt < 4; ++kt) {
        const int col = n0 + wk + kt*16 + fr;
        const float val = acc[qt][kt][j] + bcol[kt];
        const size_t idx =
            (((size_t)(b*Hc + (col >> 6)))*Tc + tt)*Dc + (col & 63);
        if (z < 2) {
          const unsigned short hb = bf16rne(val);
          dh[idx] = hb;
          dl[idx] = bf16rne(val - bf16tof(hb));
        } else {
          V[idx] = val;
        }
      }
    }
  }
}

// ---------------------------------------------------------------------------
// K2a: scores = 0.125 * Q @ K^T per (b,h), split-bf16 MFMA, staging direct
// from the bf16 hi/lo planes written by qkv_mfma (no conversion in-kernel).
// ---------------------------------------------------------------------------
__global__ __launch_bounds__(256) void score_mfma(
    const unsigned short* __restrict__ qhp, const unsigned short* __restrict__ qlp,
    const unsigned short* __restrict__ khp, const unsigned short* __restrict__ klp,
    float* __restrict__ scores)
{
  const int k0 = blockIdx.x * 128;
  const int q0 = blockIdx.y * 64;
  const int bh = blockIdx.z;

  __shared__ unsigned short Qh[64][72],  Ql[64][72];
  __shared__ unsigned short Kh[128][72], Kl[128][72];

  const int t = threadIdx.x;
  const size_t qb = ((size_t)bh*Tc + q0) * Dc;
  const size_t kb = ((size_t)bh*Tc + k0) * Dc;

  #pragma unroll
  for (int i = 0; i < 2; ++i) {
    const int id = t + 256*i;
    const int r = id >> 3, c8 = (id & 7) * 8;
    *(u16x8*)&Qh[r][c8] = *(const u16x8*)&qhp[qb + (size_t)r*Dc + c8];
    *(u16x8*)&Ql[r][c8] = *(const u16x8*)&qlp[qb + (size_t)r*Dc + c8];
  }
  #pragma unroll
  for (int i = 0; i < 4; ++i) {
    const int id = t + 256*i;
    const int r = id >> 3, c8 = (id & 7) * 8;
    *(u16x8*)&Kh[r][c8] = *(const u16x8*)&khp[kb + (size_t)r*Dc + c8];
    *(u16x8*)&Kl[r][c8] = *(const u16x8*)&klp[kb + (size_t)r*Dc + c8];
  }
  __syncthreads();

  const int lane = t & 63;
  const int wv   = t >> 6;
  const int wq   = (wv >> 1) * 32;
  const int wk   = (wv & 1) * 64;
  const int fr   = lane & 15;
  const int fg   = lane >> 4;

  f32x4 acc[2][4] = {};

  #pragma unroll
  for (int g2 = 0; g2 < 2; ++g2) {
    const int dof = g2*32 + 8*fg;
    bf16x8 aH[2], aL[2];
    #pragma unroll
    for (int qt = 0; qt < 2; ++qt) {
      aH[qt] = *(const bf16x8*)&Qh[wq + qt*16 + fr][dof];
      aL[qt] = *(const bf16x8*)&Ql[wq + qt*16 + fr][dof];
    }
    #pragma unroll
    for (int kt = 0; kt < 4; ++kt) {
      const bf16x8 bH = *(const bf16x8*)&Kh[wk + kt*16 + fr][dof];
      const bf16x8 bL = *(const bf16x8*)&Kl[wk + kt*16 + fr][dof];
      #pragma unroll
      for (int qt = 0; qt < 2; ++qt) {
        acc[qt][kt] = __builtin_amdgcn_mfma_f32_16x16x32_bf16(
            aH[qt], bH, acc[qt][kt], 0, 0, 0);
        acc[qt][kt] = __builtin_amdgcn_mfma_f32_16x16x32_bf16(
            aH[qt], bL, acc[qt][kt], 0, 0, 0);
        acc[qt][kt] = __builtin_amdgcn_mfma_f32_16x16x32_bf16(
            aL[qt], bH, acc[qt][kt], 0, 0, 0);
      }
    }
  }

  #pragma unroll
  for (int qt = 0; qt < 2; ++qt) {
    #pragma unroll
    for (int j = 0; j < 4; ++j) {
      const int qrow = q0 + wq + qt*16 + 4*fg + j;
      const size_t rb = ((size_t)bh * Tc + qrow) * Tc + k0 + wk;
      #pragma unroll
      for (int kt = 0; kt < 4; ++kt)
        scores[rb + kt*16 + fr] = acc[qt][kt][j] * 0.125f;
    }
  }
}

// ---------------------------------------------------------------------------
// K2b: streaming softmax + UCB top-k + renorm + count + sparse PV.
// (byte-identical to round 7)
// ---------------------------------------------------------------------------
__global__ __launch_bounds__(256, 4) void ucb_topk(
    const float* __restrict__ qkv,
    const float* __restrict__ count_in,
    const int*   __restrict__ counter_p,
    const int*   __restrict__ ucb_p,
    float* __restrict__ probs,          // in: scaled scores; out: probs
    float* __restrict__ count_out,
    float* __restrict__ ctx)
{
  const int bh   = blockIdx.y;
  const int lane = threadIdx.x & 63;
  const int wv   = threadIdx.x >> 6;
  const int row  = blockIdx.x * 4 + wv;
  const int b = bh / Hc, h = bh % Hc;
  const size_t rb = ((size_t)bh * Tc + row) * Tc;
  const float* __restrict__ Vh = qkv + 2*BTC + (size_t)bh * Tc * Dc;

  const int  counter = counter_p[0];
  const int  ucbf    = ucb_p[0];
  const bool do_ucb  = (ucbf != 0) && (counter >= 1000);
  const float lt     = do_ucb ? logf((float)counter) : 0.f;

  float s[16], cnt[16];
  #pragma unroll
  for (int w = 0; w < 16; ++w) s[w]   = probs[rb + lane + 64*w];
  #pragma unroll
  for (int w = 0; w < 16; ++w) cnt[w] = count_in[rb + lane + 64*w];

  float mx = -INFINITY;
  #pragma unroll
  for (int w = 0; w < 16; ++w) mx = fmaxf(mx, s[w]);
  #pragma unroll
  for (int off = 32; off > 0; off >>= 1) mx = fmaxf(mx, __shfl_xor(mx, off));

  float sum = 0.f;
  #pragma unroll
  for (int w = 0; w < 16; ++w) { s[w] = __expf(s[w] - mx); sum += s[w]; }
  #pragma unroll
  for (int off = 32; off > 0; off >>= 1) sum += __shfl_xor(sum, off);

  const float rsum = 1.0f / sum;
  #pragma unroll
  for (int w = 0; w < 16; ++w) s[w] = s[w] * rsum;     // att

  if (do_ucb) {
    float u[16];
    #pragma unroll
    for (int w = 0; w < 16; ++w)
      u[w] = s[w] + sqrtf(lt / (cnt[w] + 1e-8f));

    float pvv[KSEL];
    int   kvv[KSEL];
    unsigned sel = 0u;
    #pragma unroll
    for (int r = 0; r < KSEL; ++r) {
      float bu = -INFINITY, bs = 0.f; int bk = 1 << 30;
      #pragma unroll
      for (int w = 0; w < 16; ++w) {
        if (!((sel >> w) & 1u)) {
          const int kk = lane + 64*w;
          if (u[w] > bu || (u[w] == bu && kk < bk)) {
            bu = u[w]; bs = s[w]; bk = kk;
          }
        }
      }
      #pragma unroll
      for (int off = 32; off > 0; off >>= 1) {
        const float ov = __shfl_xor(bu, off);
        const float os = __shfl_xor(bs, off);
        const int   ok = __shfl_xor(bk, off);
        if (ov > bu || (ov == bu && ok < bk)) { bu = ov; bs = os; bk = ok; }
      }
      if ((bk & 63) == lane) sel |= 1u << (bk >> 6);
      pvv[r] = bs; kvv[r] = bk;
    }

    float denom = 1e-8f;
    #pragma unroll
    for (int r = 0; r < KSEL; ++r) denom += pvv[r];
    const float rden = 1.0f / denom;

    #pragma unroll
    for (int w = 0; w < 16; ++w) {
      const bool sb = (sel >> w) & 1u;
      probs[rb + lane + 64*w]     = sb ? (s[w] * rden) : 0.0f;
      count_out[rb + lane + 64*w] = cnt[w] + (sb ? 1.0f : 0.0f);
    }

    float cd = 0.f;
    #pragma unroll
    for (int r = 0; r < KSEL; ++r)
      cd += pvv[r] * Vh[(size_t)kvv[r] * Dc + lane];
    ctx[((size_t)b*Tc + row)*Cch + h*Dc + lane] = cd * rden;
  } else {
    #pragma unroll
    for (int w = 0; w < 16; ++w) {
      probs[rb + lane + 64*w]     = s[w];
      count_out[rb + lane + 64*w] = cnt[w];
    }
  }
}

// ---------------------------------------------------------------------------
// K3 (fallback only, non-UCB path): ctx = probs @ V per (b,h).
// ---------------------------------------------------------------------------
__global__ __launch_bounds__(256) void pv_gemm(
    const float* __restrict__ probs,
    const float* __restrict__ Vm,
    float* __restrict__ ctx,
    const int* __restrict__ counter_p,
    const int* __restrict__ ucb_p)
{
  if ((ucb_p[0] != 0) && (counter_p[0] >= 1000)) return;  // K2b did sparse PV

  const int bh = blockIdx.y;
  const int q0 = blockIdx.x * 64;
  const int b = bh / Hc, h = bh % Hc;

  __shared__ float aT[32][68];
  __shared__ float vN[32][68];

  const int t  = threadIdx.x;
  const int tn = t & 15;
  const int tq = t >> 4;

  float acc[4][4];
  #pragma unroll
  for (int i = 0; i < 4; ++i)
    #pragma unroll
    for (int j = 0; j < 4; ++j) acc[i][j] = 0.f;

  for (int k0 = 0; k0 < Tc; k0 += 32) {
    __syncthreads();
    #pragma unroll
    for (int p = 0; p < 2; ++p) {
      const int id = t + 256*p;
      const int r = id >> 3, c = id & 7;
      const float4 v =
          *(const float4*)&probs[((size_t)bh*Tc + q0 + r)*Tc + k0 + 4*c];
      aT[4*c + 0][r] = v.x; aT[4*c + 1][r] = v.y;
      aT[4*c + 2][r] = v.z; aT[4*c + 3][r] = v.w;
    }
    #pragma unroll
    for (int p = 0; p < 2; ++p) {
      const int id = t + 256*p;
      const int kk = id >> 4, dcc = id & 15;
      const float4 v = *(const float4*)&Vm[((size_t)bh*Tc + k0 + kk)*Dc + 4*dcc];
      *(float4*)&vN[kk][4*dcc] = v;
    }
    __syncthreads();
    #pragma unroll
    for (int kk = 0; kk < 32; ++kk) {
      const float4 a  = *(const float4*)&aT[kk][4*tq];
      const float4 vv = *(const float4*)&vN[kk][4*tn];
      const float av[4] = {a.x, a.y, a.z, a.w};
      const float bw[4] = {vv.x, vv.y, vv.z, vv.w};
      #pragma unroll
      for (int qi = 0; qi < 4; ++qi)
        #pragma unroll
        for (int ni = 0; ni < 4; ++ni) acc[qi][ni] += av[qi] * bw[ni];
    }
  }

  #pragma unroll
  for (int qi = 0; qi < 4; ++qi) {
    const int tt = q0 + 4*tq + qi;
    float4 o;
    o.x = acc[qi][0]; o.y = acc[qi][1]; o.z = acc[qi][2]; o.w = acc[qi][3];
    *(float4*)&ctx[((size_t)b*Tc + tt)*Cch + h*Dc + 4*tn] = o;
  }
}

// ---------------------------------------------------------------------------
// out_mfma: out = ctx @ Wo + bo, split-bf16 MFMA.  A = ctx planes [m][k],
// B = Wo^T planes [n][k].  Same skeleton as qkv_mfma; plain f32 output.
// ---------------------------------------------------------------------------
__global__ __launch_bounds__(256) void out_mfma(
    const unsigned short* __restrict__ ah, const unsigned short* __restrict__ al,
    const unsigned short* __restrict__ bth, const unsigned short* __restrict__ btl,
    const float* __restrict__ bias,
    float* __restrict__ out)
{
  const int m0 = blockIdx.y * 64;
  const int n0 = blockIdx.x * 128;

  __shared__ unsigned short Ah[64][72],  Al[64][72];
  __shared__ unsigned short Bh[128][72], Bl[128][72];

  const int t    = threadIdx.x;
  const int lane = t & 63;
  const int wv   = t >> 6;
  const int wq   = (wv >> 1) * 32;
  const int wk   = (wv & 1) * 64;
  const int fr   = lane & 15;
  const int fg   = lane >> 4;

  f32x4 acc[2][4] = {};

  for (int k0 = 0; k0 < Cch; k0 += 64) {
    __syncthreads();
    #pragma unroll
    for (int i = 0; i < 2; ++i) {
      const int id = t + 256*i;
      const int r = id >> 3, c8 = (id & 7) * 8;
      *(u16x8*)&Ah[r][c8] = *(const u16x8*)&ah[(size_t)(m0 + r)*Cch + k0 + c8];
      *(u16x8*)&Al[r][c8] = *(const u16x8*)&al[(size_t)(m0 + r)*Cch + k0 + c8];
    }
    #pragma unroll
    for (int i = 0; i < 4; ++i) {
      const int id = t + 256*i;
      const int r = id >> 3, c8 = (id & 7) * 8;
      *(u16x8*)&Bh[r][c8] = *(const u16x8*)&bth[(size_t)(n0 + r)*Cch + k0 + c8];
      *(u16x8*)&Bl[r][c8] = *(const u16x8*)&btl[(size_t)(n0 + r)*Cch + k0 + c8];
    }
    __syncthreads();

    #pragma unroll
    for (int g2 = 0; g2 < 2; ++g2) {
      const int dof = g2*32 + 8*fg;
      bf16x8 aH[2], aL[2];
      #pragma unroll
      for (int qt = 0; qt < 2; ++qt) {
        aH[qt] = *(const bf16x8*)&Ah[wq + qt*16 + fr][dof];
        aL[qt] = *(const bf16x8*)&Al[wq + qt*16 + fr][dof];
      }
      #pragma unroll
      for (int kt = 0; kt < 4; ++kt) {
        const bf16x8 bH = *(const bf16x8*)&Bh[wk + kt*16 + fr][dof];
        const bf16x8 bL = *(const bf16x8*)&Bl[wk + kt*16 + fr][dof];
        #pragma unroll
        for (int qt = 0; qt < 2; ++qt) {
          acc[qt][kt] = __builtin_amdgcn_mfma_f32_16x16x32_bf16(
              aH[qt], bH, acc[qt][kt], 0, 0, 0);
          acc[qt][kt] = __builtin_amdgcn_mfma_f32_16x16x32_bf16(
              aH[qt], bL, acc[qt][kt], 0, 0, 0);
          acc[qt][kt] = __builtin_amdgcn_mfma_f32_16x16x32_bf16(
              aL[qt], bH, acc[qt][kt], 0, 0, 0);
        }
      }
    }
  }

  float bcol[4];
  #pragma unroll
  for (int kt = 0; kt < 4; ++kt) bcol[kt] = bias[n0 + wk + kt*16 + fr];

  #pragma unroll
  for (int qt = 0; qt < 2; ++qt) {
    #pragma unroll
    for (int j = 0; j < 4; ++j) {
      const int m = m0 + wq + qt*16 + 4*fg + j;
      #pragma unroll
      for (int kt = 0; kt < 4; ++kt) {
        const int col = n0 + wk + kt*16 + fr;
        out[(size_t)m * Cch + col] = acc[qt][kt][j] + bcol[kt];
      }
    }
  }
}

} // anonymous namespace

// ---------------------------------------------------------------------------
extern "C" void kernel_launch(void* const* d_in, const int* in_sizes, int n_in,
                              void* d_out, int out_size, void* d_ws, size_t ws_size,
                              hipStream_t stream) {
  (void)in_sizes; (void)n_in; (void)out_size; (void)ws_size;

  const float* hid  = (const float*)d_in[0];
  const float* cnt  = (const float*)d_in[1];
  const float* Wq   = (const float*)d_in[2];
  const float* bq   = (const float*)d_in[3];
  const float* Wk   = (const float*)d_in[4];
  const float* bk   = (const float*)d_in[5];
  const float* Wv   = (const float*)d_in[6];
  const float* bv   = (const float*)d_in[7];
  const float* Wo   = (const float*)d_in[8];
  const float* bo   = (const float*)d_in[9];
  const int* counter = (const int*)d_in[10];
  const int* ucb     = (const int*)d_in[11];

  float* out       = (float*)d_out;          // [B,T,C]
  float* probs     = out + BTC;              // [B,H,T,T] (scores, then probs)
  float* count_out = probs + PROBSN;         // [B,H,T,T]

  // workspace: Qbf16(hi|lo) | Kbf16(hi|lo) | V f32 | ctx f32 (4 x BTC f32)
  float* ws  = (float*)d_ws;
  float* V   = ws + 2*BTC;
  float* ctx = ws + 3*BTC;
  unsigned short* qkb = (unsigned short*)d_ws;
  unsigned short* qh = qkb;            // Q region (2*BTC ushort = BTC f32... x2)
  unsigned short* ql = qkb + BTC;
  unsigned short* kh = qkb + 2*BTC;    // K region
  unsigned short* kl = qkb + 3*BTC;

  // pre-convert scratch lives in the count_out region of d_out (dead until
  // ucb_topk writes it; all consumers run before ucb_topk).
  unsigned short* cvt  = (unsigned short*)count_out;
  unsigned short* hidh = cvt;
  unsigned short* hidl = cvt + BTC;
  unsigned short* wqth = cvt + 2*BTC;
  unsigned short* wqtl = wqth + CC;
  unsigned short* wkth = wqtl + CC;
  unsigned short* wktl = wkth + CC;
  unsigned short* wvth = wktl + CC;
  unsigned short* wvtl = wvth + CC;

  // post-topk converts reuse the then-dead Q/K bf16 regions.
  unsigned short* ctxh = qkb;
  unsigned short* ctxl = qkb + BTC;
  unsigned short* woth = qkb + 2*BTC;
  unsigned short* wotl = woth + CC;

  split_plane<<<BTC/1024, 256, 0, stream>>>(hid, hidh, hidl);
  splitT_w<<<dim3(24, 24), 256, 0, stream>>>(Wq, wqth, wqtl);
  splitT_w<<<dim3(24, 24), 256, 0, stream>>>(Wk, wkth, wktl);
  splitT_w<<<dim3(24, 24), 256, 0, stream>>>(Wv, wvth, wvtl);

  qkv_mfma<<<dim3(Cch/128, (Bc*Tc)/64, 3), 256, 0, stream>>>(
      hidh, hidl, wqth, wqtl, wkth, wktl, wvth, wvtl,
      bq, bk, bv, qh, ql, kh, kl, V);

  score_mfma<<<dim3(Tc/128, Tc/64, Bc*Hc), 256, 0, stream>>>(
      qh, ql, kh, kl, probs);

  ucb_topk<<<dim3(Tc/4, Bc*Hc), 256, 0, stream>>>(
      ws, cnt, counter, ucb, probs, count_out, ctx);

  pv_gemm<<<dim3(Tc/64, Bc*Hc), 256, 0, stream>>>(
      probs, V, ctx, counter, ucb);

  split_plane<<<BTC/1024, 256, 0, stream>>>(ctx, ctxh, ctxl);
  splitT_w<<<dim3(24, 24), 256, 0, stream>>>(Wo, woth, wotl);

  out_mfma<<<dim3(Cch/128, (Bc*Tc)/64), 256, 0, stream>>>(
      ctxh, ctxl, woth, wotl, bo, out);
}

// Round 9
// 389.985 us; speedup vs baseline: 15.7646x; 1.1300x over previous
//
#include <hip/hip_runtime.h>
#include <math.h>

namespace {

constexpr int Bc = 4, Tc = 1024, Cch = 768, Hc = 12, Dc = 64, KSEL = 10;
constexpr size_t BTC    = (size_t)Bc * Tc * Cch;        // 3,145,728
constexpr size_t PROBSN = (size_t)Bc * Hc * Tc * Tc;    // 50,331,648
constexpr size_t CC     = (size_t)Cch * Cch;            // 589,824

typedef __attribute__((ext_vector_type(8))) short          bf16x8;
typedef __attribute__((ext_vector_type(4))) float          f32x4;
typedef __attribute__((ext_vector_type(4))) unsigned short u16x4;
typedef __attribute__((ext_vector_type(8))) unsigned short u16x8;

// round-to-nearest-even f32 -> bf16 (raw bits); finite inputs only
__device__ __forceinline__ unsigned short bf16rne(float x) {
  unsigned int u = __float_as_uint(x);
  return (unsigned short)((u + 0x7FFFu + ((u >> 16) & 1u)) >> 16);
}
__device__ __forceinline__ float bf16tof(unsigned short h) {
  return __uint_as_float(((unsigned int)h) << 16);
}

// ---------------------------------------------------------------------------
// split_plane: f32[n] -> bf16 hi/lo planes.  n multiple of 1024.
// ---------------------------------------------------------------------------
__global__ __launch_bounds__(256) void split_plane(
    const float* __restrict__ src,
    unsigned short* __restrict__ h, unsigned short* __restrict__ l)
{
  const size_t i = (size_t)(blockIdx.x * 256 + threadIdx.x) * 4;
  const float4 v = *(const float4*)&src[i];
  const float xs[4] = {v.x, v.y, v.z, v.w};
  u16x4 hh, ll;
  #pragma unroll
  for (int e = 0; e < 4; ++e) {
    const unsigned short hb = bf16rne(xs[e]);
    hh[e] = hb;
    ll[e] = bf16rne(xs[e] - bf16tof(hb));
  }
  *(u16x4*)&h[i] = hh;
  *(u16x4*)&l[i] = ll;
}

// ---------------------------------------------------------------------------
// splitT_w: W[k][n] (768x768 f32) -> transposed bf16 planes th/tl [n][k].
// ---------------------------------------------------------------------------
__global__ __launch_bounds__(256) void splitT_w(
    const float* __restrict__ W,
    unsigned short* __restrict__ th, unsigned short* __restrict__ tl)
{
  __shared__ float tile[32][33];
  const int n0 = blockIdx.x * 32, k0 = blockIdx.y * 32;
  const int x = threadIdx.x & 31, y = threadIdx.x >> 5;   // y 0..7

  #pragma unroll
  for (int i = 0; i < 4; ++i) {
    const int kk = y * 4 + i;
    tile[kk][x] = W[(size_t)(k0 + kk) * Cch + n0 + x];
  }
  __syncthreads();
  #pragma unroll
  for (int i = 0; i < 4; ++i) {
    const int nn = y * 4 + i;
    const float v = tile[x][nn];                          // = W[k0+x][n0+nn]
    const unsigned short hb = bf16rne(v);
    th[(size_t)(n0 + nn) * Cch + k0 + x] = hb;
    tl[(size_t)(n0 + nn) * Cch + k0 + x] = bf16rne(v - bf16tof(hb));
  }
}

// ---------------------------------------------------------------------------
// qkv_mfma: [Q|K|V] = hid @ W + b, split-bf16 MFMA.  (unchanged from round 8)
// ---------------------------------------------------------------------------
__global__ __launch_bounds__(256) void qkv_mfma(
    const unsigned short* __restrict__ hidh, const unsigned short* __restrict__ hidl,
    const unsigned short* __restrict__ wqth, const unsigned short* __restrict__ wqtl,
    const unsigned short* __restrict__ wkth, const unsigned short* __restrict__ wktl,
    const unsigned short* __restrict__ wvth, const unsigned short* __restrict__ wvtl,
    const float* __restrict__ bq, const float* __restrict__ bk,
    const float* __restrict__ bv,
    unsigned short* __restrict__ qh, unsigned short* __restrict__ ql,
    unsigned short* __restrict__ kh, unsigned short* __restrict__ kl,
    float* __restrict__ V)
{
  const int z = blockIdx.z;
  const unsigned short* __restrict__ Bhp = (z == 0) ? wqth : (z == 1) ? wkth : wvth;
  const unsigned short* __restrict__ Blp = (z == 0) ? wqtl : (z == 1) ? wktl : wvtl;
  const float* __restrict__ bias = (z == 0) ? bq : (z == 1) ? bk : bv;

  const int m0 = blockIdx.y * 64;
  const int n0 = blockIdx.x * 128;

  __shared__ unsigned short Ah[64][72],  Al[64][72];
  __shared__ unsigned short Bh[128][72], Bl[128][72];

  const int t    = threadIdx.x;
  const int lane = t & 63;
  const int wv   = t >> 6;
  const int wq   = (wv >> 1) * 32;
  const int wk   = (wv & 1) * 64;
  const int fr   = lane & 15;
  const int fg   = lane >> 4;

  f32x4 acc[2][4] = {};

  for (int k0 = 0; k0 < Cch; k0 += 64) {
    __syncthreads();
    #pragma unroll
    for (int i = 0; i < 2; ++i) {       // A: 64x64 x 2 planes
      const int id = t + 256*i;
      const int r = id >> 3, c8 = (id & 7) * 8;
      *(u16x8*)&Ah[r][c8] = *(const u16x8*)&hidh[(size_t)(m0 + r)*Cch + k0 + c8];
      *(u16x8*)&Al[r][c8] = *(const u16x8*)&hidl[(size_t)(m0 + r)*Cch + k0 + c8];
    }
    #pragma unroll
    for (int i = 0; i < 4; ++i) {       // B: 128x64 x 2 planes
      const int id = t + 256*i;
      const int r = id >> 3, c8 = (id & 7) * 8;
      *(u16x8*)&Bh[r][c8] = *(const u16x8*)&Bhp[(size_t)(n0 + r)*Cch + k0 + c8];
      *(u16x8*)&Bl[r][c8] = *(const u16x8*)&Blp[(size_t)(n0 + r)*Cch + k0 + c8];
    }
    __syncthreads();

    #pragma unroll
    for (int g2 = 0; g2 < 2; ++g2) {
      const int dof = g2*32 + 8*fg;
      bf16x8 aH[2], aL[2];
      #pragma unroll
      for (int qt = 0; qt < 2; ++qt) {
        aH[qt] = *(const bf16x8*)&Ah[wq + qt*16 + fr][dof];
        aL[qt] = *(const bf16x8*)&Al[wq + qt*16 + fr][dof];
      }
      #pragma unroll
      for (int kt = 0; kt < 4; ++kt) {
        const bf16x8 bH = *(const bf16x8*)&Bh[wk + kt*16 + fr][dof];
        const bf16x8 bL = *(const bf16x8*)&Bl[wk + kt*16 + fr][dof];
        #pragma unroll
        for (int qt = 0; qt < 2; ++qt) {
          acc[qt][kt] = __builtin_amdgcn_mfma_f32_16x16x32_bf16(
              aH[qt], bH, acc[qt][kt], 0, 0, 0);
          acc[qt][kt] = __builtin_amdgcn_mfma_f32_16x16x32_bf16(
              aH[qt], bL, acc[qt][kt], 0, 0, 0);
          acc[qt][kt] = __builtin_amdgcn_mfma_f32_16x16x32_bf16(
              aL[qt], bH, acc[qt][kt], 0, 0, 0);
        }
      }
    }
  }

  float bcol[4];
  #pragma unroll
  for (int kt = 0; kt < 4; ++kt) bcol[kt] = bias[n0 + wk + kt*16 + fr];

  unsigned short* __restrict__ dh = (z == 0) ? qh : kh;
  unsigned short* __restrict__ dl = (z == 0) ? ql : kl;

  #pragma unroll
  for (int qt = 0; qt < 2; ++qt) {
    #pragma unroll
    for (int j = 0; j < 4; ++j) {
      const int m  = m0 + wq + qt*16 + 4*fg + j;
      const int b  = m >> 10, tt = m & 1023;
      #pragma unroll
      for (int kt = 0; kt < 4; ++kt) {
        const int col = n0 + wk + kt*16 + fr;
        const float val = acc[qt][kt][j] + bcol[kt];
        const size_t idx =
            (((size_t)(b*Hc + (col >> 6)))*Tc + tt)*Dc + (col & 63);
        if (z < 2) {
          const unsigned short hb = bf16rne(val);
          dh[idx] = hb;
          dl[idx] = bf16rne(val - bf16tof(hb));
        } else {
          V[idx] = val;
        }
      }
    }
  }
}

// ---------------------------------------------------------------------------
// K2a: scores = 0.125 * Q @ K^T, split-bf16 MFMA.  (unchanged from round 8)
// ---------------------------------------------------------------------------
__global__ __launch_bounds__(256) void score_mfma(
    const unsigned short* __restrict__ qhp, const unsigned short* __restrict__ qlp,
    const unsigned short* __restrict__ khp, const unsigned short* __restrict__ klp,
    float* __restrict__ scores)
{
  const int k0 = blockIdx.x * 128;
  const int q0 = blockIdx.y * 64;
  const int bh = blockIdx.z;

  __shared__ unsigned short Qh[64][72],  Ql[64][72];
  __shared__ unsigned short Kh[128][72], Kl[128][72];

  const int t = threadIdx.x;
  const size_t qb = ((size_t)bh*Tc + q0) * Dc;
  const size_t kb = ((size_t)bh*Tc + k0) * Dc;

  #pragma unroll
  for (int i = 0; i < 2; ++i) {
    const int id = t + 256*i;
    const int r = id >> 3, c8 = (id & 7) * 8;
    *(u16x8*)&Qh[r][c8] = *(const u16x8*)&qhp[qb + (size_t)r*Dc + c8];
    *(u16x8*)&Ql[r][c8] = *(const u16x8*)&qlp[qb + (size_t)r*Dc + c8];
  }
  #pragma unroll
  for (int i = 0; i < 4; ++i) {
    const int id = t + 256*i;
    const int r = id >> 3, c8 = (id & 7) * 8;
    *(u16x8*)&Kh[r][c8] = *(const u16x8*)&khp[kb + (size_t)r*Dc + c8];
    *(u16x8*)&Kl[r][c8] = *(const u16x8*)&klp[kb + (size_t)r*Dc + c8];
  }
  __syncthreads();

  const int lane = t & 63;
  const int wv   = t >> 6;
  const int wq   = (wv >> 1) * 32;
  const int wk   = (wv & 1) * 64;
  const int fr   = lane & 15;
  const int fg   = lane >> 4;

  f32x4 acc[2][4] = {};

  #pragma unroll
  for (int g2 = 0; g2 < 2; ++g2) {
    const int dof = g2*32 + 8*fg;
    bf16x8 aH[2], aL[2];
    #pragma unroll
    for (int qt = 0; qt < 2; ++qt) {
      aH[qt] = *(const bf16x8*)&Qh[wq + qt*16 + fr][dof];
      aL[qt] = *(const bf16x8*)&Ql[wq + qt*16 + fr][dof];
    }
    #pragma unroll
    for (int kt = 0; kt < 4; ++kt) {
      const bf16x8 bH = *(const bf16x8*)&Kh[wk + kt*16 + fr][dof];
      const bf16x8 bL = *(const bf16x8*)&Kl[wk + kt*16 + fr][dof];
      #pragma unroll
      for (int qt = 0; qt < 2; ++qt) {
        acc[qt][kt] = __builtin_amdgcn_mfma_f32_16x16x32_bf16(
            aH[qt], bH, acc[qt][kt], 0, 0, 0);
        acc[qt][kt] = __builtin_amdgcn_mfma_f32_16x16x32_bf16(
            aH[qt], bL, acc[qt][kt], 0, 0, 0);
        acc[qt][kt] = __builtin_amdgcn_mfma_f32_16x16x32_bf16(
            aL[qt], bH, acc[qt][kt], 0, 0, 0);
      }
    }
  }

  #pragma unroll
  for (int qt = 0; qt < 2; ++qt) {
    #pragma unroll
    for (int j = 0; j < 4; ++j) {
      const int qrow = q0 + wq + qt*16 + 4*fg + j;
      const size_t rb = ((size_t)bh * Tc + qrow) * Tc + k0 + wk;
      #pragma unroll
      for (int kt = 0; kt < 4; ++kt)
        scores[rb + kt*16 + fr] = acc[qt][kt][j] * 0.125f;
    }
  }
}

// ---------------------------------------------------------------------------
// K2b: streaming softmax + UCB top-k + renorm + count + sparse PV.
// One wave per q-row.  NEW: u64-packed (u_bits, ~idx) keys -> 2-shfl
// butterfly with free lowest-index tie-break; rsqrt bonus; cnt streamed out
// early (+1 fix-up on 10 owners); winner s recovered via LDS + rpack nibble.
// ---------------------------------------------------------------------------
__global__ __launch_bounds__(256, 4) void ucb_topk(
    const float* __restrict__ qkv,
    const float* __restrict__ count_in,
    const int*   __restrict__ counter_p,
    const int*   __restrict__ ucb_p,
    float* __restrict__ probs,          // in: scaled scores; out: probs
    float* __restrict__ count_out,
    float* __restrict__ ctx)
{
  const int bh   = blockIdx.y;
  const int lane = threadIdx.x & 63;
  const int wv   = threadIdx.x >> 6;
  const int row  = blockIdx.x * 4 + wv;
  const int b = bh / Hc, h = bh % Hc;
  const size_t rb = ((size_t)bh * Tc + row) * Tc;
  const float* __restrict__ Vh = qkv + 2*BTC + (size_t)bh * Tc * Dc;

  __shared__ float psel[4][KSEL];     // winner s values, per row-in-block

  const int  counter = counter_p[0];
  const int  ucbf    = ucb_p[0];
  const bool do_ucb  = (ucbf != 0) && (counter >= 1000);
  const float lt     = do_ucb ? logf((float)counter) : 0.f;

  float s[16];
  #pragma unroll
  for (int w = 0; w < 16; ++w) s[w] = probs[rb + lane + 64*w];

  // softmax (scores already scaled by 0.125 in score_mfma)
  float mx = -INFINITY;
  #pragma unroll
  for (int w = 0; w < 16; ++w) mx = fmaxf(mx, s[w]);
  #pragma unroll
  for (int off = 32; off > 0; off >>= 1) mx = fmaxf(mx, __shfl_xor(mx, off));

  float sum = 0.f;
  #pragma unroll
  for (int w = 0; w < 16; ++w) { s[w] = __expf(s[w] - mx); sum += s[w]; }
  #pragma unroll
  for (int off = 32; off > 0; off >>= 1) sum += __shfl_xor(sum, off);

  const float rsum = 1.0f / sum;
  #pragma unroll
  for (int w = 0; w < 16; ++w) s[w] = s[w] * rsum;     // att

  if (do_ucb) {
    const float sqlt = sqrtf(lt);

    // build u64 keys; stream count through (write count_out = count_in now,
    // fix up the 10 selected later) so cnt[16] never stays live.
    unsigned long long key[16];
    #pragma unroll
    for (int w = 0; w < 16; ++w) {
      const float c = count_in[rb + lane + 64*w];
      count_out[rb + lane + 64*w] = c;
      const float u = fmaf(sqlt, rsqrtf(c + 1e-8f), s[w]);
      key[w] = ((unsigned long long)__float_as_uint(u) << 32)
             | (unsigned long long)(~(unsigned)(lane + (w << 6)));
    }

    unsigned selmask = 0u;
    unsigned long long rpack = 0ull;   // 4-bit round id per w slot
    int ks[KSEL];                      // wave-uniform selected indices (SGPR)

    #pragma unroll
    for (int r = 0; r < KSEL; ++r) {
      // local max over unselected (zero-under-mask; valid keys are nonzero)
      unsigned long long m = 0ull;
      #pragma unroll
      for (int w = 0; w < 16; ++w) {
        const unsigned long long kw =
            ((selmask >> w) & 1u) ? 0ull : key[w];
        m = (kw > m) ? kw : m;
      }
      // butterfly max (2 shfl per step; tie-break baked into key)
      #pragma unroll
      for (int off = 32; off > 0; off >>= 1) {
        const unsigned long long o = __shfl_xor(m, off);
        m = (o > m) ? o : m;
      }
      const int idx = (int)(~(unsigned)(m & 0xFFFFFFFFull));
      ks[r] = __builtin_amdgcn_readfirstlane(idx);
      if ((idx & 63) == lane) {
        const int wsel = idx >> 6;
        selmask |= (1u << wsel);
        rpack   |= ((unsigned long long)r << (wsel * 4));
      }
    }

    // publish winner s values (owner lanes) to LDS, keyed by round id
    #pragma unroll
    for (int w = 0; w < 16; ++w) {
      if ((selmask >> w) & 1u) {
        const int r = (int)((rpack >> (4 * w)) & 15ull);
        psel[wv][r] = s[w];
      }
    }
    __syncthreads();    // do_ucb is grid-uniform; all waves reach this

    float pvv[KSEL];
    float denom = 1e-8f;
    #pragma unroll
    for (int r = 0; r < KSEL; ++r) { pvv[r] = psel[wv][r]; denom += pvv[r]; }
    const float rden = 1.0f / denom;

    // probs write + count fix-up
    #pragma unroll
    for (int w = 0; w < 16; ++w) {
      const bool sb = (selmask >> w) & 1u;
      probs[rb + lane + 64*w] = sb ? (s[w] * rden) : 0.0f;
    }
    #pragma unroll
    for (int r = 0; r < KSEL; ++r) {
      if ((ks[r] & 63) == lane)
        count_out[rb + ks[r]] = count_in[rb + ks[r]] + 1.0f;
    }

    // sparse PV: ctx[d=lane] = (sum_r pvv[r] * V[ks[r]][d]) * rden
    float cd = 0.f;
    #pragma unroll
    for (int r = 0; r < KSEL; ++r)
      cd += pvv[r] * Vh[(size_t)ks[r] * Dc + lane];
    ctx[((size_t)b*Tc + row)*Cch + h*Dc + lane] = cd * rden;
  } else {
    #pragma unroll
    for (int w = 0; w < 16; ++w) {
      probs[rb + lane + 64*w]     = s[w];
      count_out[rb + lane + 64*w] = count_in[rb + lane + 64*w];
    }
  }
}

// ---------------------------------------------------------------------------
// K3 (fallback only, non-UCB path): ctx = probs @ V per (b,h).
// ---------------------------------------------------------------------------
__global__ __launch_bounds__(256) void pv_gemm(
    const float* __restrict__ probs,
    const float* __restrict__ Vm,
    float* __restrict__ ctx,
    const int* __restrict__ counter_p,
    const int* __restrict__ ucb_p)
{
  if ((ucb_p[0] != 0) && (counter_p[0] >= 1000)) return;  // K2b did sparse PV

  const int bh = blockIdx.y;
  const int q0 = blockIdx.x * 64;
  const int b = bh / Hc, h = bh % Hc;

  __shared__ float aT[32][68];
  __shared__ float vN[32][68];

  const int t  = threadIdx.x;
  const int tn = t & 15;
  const int tq = t >> 4;

  float acc[4][4];
  #pragma unroll
  for (int i = 0; i < 4; ++i)
    #pragma unroll
    for (int j = 0; j < 4; ++j) acc[i][j] = 0.f;

  for (int k0 = 0; k0 < Tc; k0 += 32) {
    __syncthreads();
    #pragma unroll
    for (int p = 0; p < 2; ++p) {
      const int id = t + 256*p;
      const int r = id >> 3, c = id & 7;
      const float4 v =
          *(const float4*)&probs[((size_t)bh*Tc + q0 + r)*Tc + k0 + 4*c];
      aT[4*c + 0][r] = v.x; aT[4*c + 1][r] = v.y;
      aT[4*c + 2][r] = v.z; aT[4*c + 3][r] = v.w;
    }
    #pragma unroll
    for (int p = 0; p < 2; ++p) {
      const int id = t + 256*p;
      const int kk = id >> 4, dcc = id & 15;
      const float4 v = *(const float4*)&Vm[((size_t)bh*Tc + k0 + kk)*Dc + 4*dcc];
      *(float4*)&vN[kk][4*dcc] = v;
    }
    __syncthreads();
    #pragma unroll
    for (int kk = 0; kk < 32; ++kk) {
      const float4 a  = *(const float4*)&aT[kk][4*tq];
      const float4 vv = *(const float4*)&vN[kk][4*tn];
      const float av[4] = {a.x, a.y, a.z, a.w};
      const float bw[4] = {vv.x, vv.y, vv.z, vv.w};
      #pragma unroll
      for (int qi = 0; qi < 4; ++qi)
        #pragma unroll
        for (int ni = 0; ni < 4; ++ni) acc[qi][ni] += av[qi] * bw[ni];
    }
  }

  #pragma unroll
  for (int qi = 0; qi < 4; ++qi) {
    const int tt = q0 + 4*tq + qi;
    float4 o;
    o.x = acc[qi][0]; o.y = acc[qi][1]; o.z = acc[qi][2]; o.w = acc[qi][3];
    *(float4*)&ctx[((size_t)b*Tc + tt)*Cch + h*Dc + 4*tn] = o;
  }
}

// ---------------------------------------------------------------------------
// out_mfma: out = ctx @ Wo + bo, split-bf16 MFMA.  (unchanged from round 8)
// ---------------------------------------------------------------------------
__global__ __launch_bounds__(256) void out_mfma(
    const unsigned short* __restrict__ ah, const unsigned short* __restrict__ al,
    const unsigned short* __restrict__ bth, const unsigned short* __restrict__ btl,
    const float* __restrict__ bias,
    float* __restrict__ out)
{
  const int m0 = blockIdx.y * 64;
  const int n0 = blockIdx.x * 128;

  __shared__ unsigned short Ah[64][72],  Al[64][72];
  __shared__ unsigned short Bh[128][72], Bl[128][72];

  const int t    = threadIdx.x;
  const int lane = t & 63;
  const int wv   = t >> 6;
  const int wq   = (wv >> 1) * 32;
  const int wk   = (wv & 1) * 64;
  const int fr   = lane & 15;
  const int fg   = lane >> 4;

  f32x4 acc[2][4] = {};

  for (int k0 = 0; k0 < Cch; k0 += 64) {
    __syncthreads();
    #pragma unroll
    for (int i = 0; i < 2; ++i) {
      const int id = t + 256*i;
      const int r = id >> 3, c8 = (id & 7) * 8;
      *(u16x8*)&Ah[r][c8] = *(const u16x8*)&ah[(size_t)(m0 + r)*Cch + k0 + c8];
      *(u16x8*)&Al[r][c8] = *(const u16x8*)&al[(size_t)(m0 + r)*Cch + k0 + c8];
    }
    #pragma unroll
    for (int i = 0; i < 4; ++i) {
      const int id = t + 256*i;
      const int r = id >> 3, c8 = (id & 7) * 8;
      *(u16x8*)&Bh[r][c8] = *(const u16x8*)&bth[(size_t)(n0 + r)*Cch + k0 + c8];
      *(u16x8*)&Bl[r][c8] = *(const u16x8*)&btl[(size_t)(n0 + r)*Cch + k0 + c8];
    }
    __syncthreads();

    #pragma unroll
    for (int g2 = 0; g2 < 2; ++g2) {
      const int dof = g2*32 + 8*fg;
      bf16x8 aH[2], aL[2];
      #pragma unroll
      for (int qt = 0; qt < 2; ++qt) {
        aH[qt] = *(const bf16x8*)&Ah[wq + qt*16 + fr][dof];
        aL[qt] = *(const bf16x8*)&Al[wq + qt*16 + fr][dof];
      }
      #pragma unroll
      for (int kt = 0; kt < 4; ++kt) {
        const bf16x8 bH = *(const bf16x8*)&Bh[wk + kt*16 + fr][dof];
        const bf16x8 bL = *(const bf16x8*)&Bl[wk + kt*16 + fr][dof];
        #pragma unroll
        for (int qt = 0; qt < 2; ++qt) {
          acc[qt][kt] = __builtin_amdgcn_mfma_f32_16x16x32_bf16(
              aH[qt], bH, acc[qt][kt], 0, 0, 0);
          acc[qt][kt] = __builtin_amdgcn_mfma_f32_16x16x32_bf16(
              aH[qt], bL, acc[qt][kt], 0, 0, 0);
          acc[qt][kt] = __builtin_amdgcn_mfma_f32_16x16x32_bf16(
              aL[qt], bH, acc[qt][kt], 0, 0, 0);
        }
      }
    }
  }

  float bcol[4];
  #pragma unroll
  for (int kt = 0; kt < 4; ++kt) bcol[kt] = bias[n0 + wk + kt*16 + fr];

  #pragma unroll
  for (int qt = 0; qt < 2; ++qt) {
    #pragma unroll
    for (int j = 0; j < 4; ++j) {
      const int m = m0 + wq + qt*16 + 4*fg + j;
      #pragma unroll
      for (int kt = 0; kt < 4; ++kt) {
        const int col = n0 + wk + kt*16 + fr;
        out[(size_t)m * Cch + col] = acc[qt][kt][j] + bcol[kt];
      }
    }
  }
}

} // anonymous namespace

// ---------------------------------------------------------------------------
extern "C" void kernel_launch(void* const* d_in, const int* in_sizes, int n_in,
                              void* d_out, int out_size, void* d_ws, size_t ws_size,
                              hipStream_t stream) {
  (void)in_sizes; (void)n_in; (void)out_size; (void)ws_size;

  const float* hid  = (const float*)d_in[0];
  const float* cnt  = (const float*)d_in[1];
  const float* Wq   = (const float*)d_in[2];
  const float* bq   = (const float*)d_in[3];
  const float* Wk   = (const float*)d_in[4];
  const float* bk   = (const float*)d_in[5];
  const float* Wv   = (const float*)d_in[6];
  const float* bv   = (const float*)d_in[7];
  const float* Wo   = (const float*)d_in[8];
  const float* bo   = (const float*)d_in[9];
  const int* counter = (const int*)d_in[10];
  const int* ucb     = (const int*)d_in[11];

  float* out       = (float*)d_out;          // [B,T,C]
  float* probs     = out + BTC;              // [B,H,T,T] (scores, then probs)
  float* count_out = probs + PROBSN;         // [B,H,T,T]

  // workspace: Qbf16(hi|lo) | Kbf16(hi|lo) | V f32 | ctx f32 (4 x BTC f32)
  float* ws  = (float*)d_ws;
  float* V   = ws + 2*BTC;
  float* ctx = ws + 3*BTC;
  unsigned short* qkb = (unsigned short*)d_ws;
  unsigned short* qh = qkb;
  unsigned short* ql = qkb + BTC;
  unsigned short* kh = qkb + 2*BTC;
  unsigned short* kl = qkb + 3*BTC;

  // pre-convert scratch lives in the count_out region of d_out (dead until
  // ucb_topk writes it; all consumers run before ucb_topk).
  unsigned short* cvt  = (unsigned short*)count_out;
  unsigned short* hidh = cvt;
  unsigned short* hidl = cvt + BTC;
  unsigned short* wqth = cvt + 2*BTC;
  unsigned short* wqtl = wqth + CC;
  unsigned short* wkth = wqtl + CC;
  unsigned short* wktl = wkth + CC;
  unsigned short* wvth = wktl + CC;
  unsigned short* wvtl = wvth + CC;

  // post-topk converts reuse the then-dead Q/K bf16 regions.
  unsigned short* ctxh = qkb;
  unsigned short* ctxl = qkb + BTC;
  unsigned short* woth = qkb + 2*BTC;
  unsigned short* wotl = woth + CC;

  split_plane<<<BTC/1024, 256, 0, stream>>>(hid, hidh, hidl);
  splitT_w<<<dim3(24, 24), 256, 0, stream>>>(Wq, wqth, wqtl);
  splitT_w<<<dim3(24, 24), 256, 0, stream>>>(Wk, wkth, wktl);
  splitT_w<<<dim3(24, 24), 256, 0, stream>>>(Wv, wvth, wvtl);

  qkv_mfma<<<dim3(Cch/128, (Bc*Tc)/64, 3), 256, 0, stream>>>(
      hidh, hidl, wqth, wqtl, wkth, wktl, wvth, wvtl,
      bq, bk, bv, qh, ql, kh, kl, V);

  score_mfma<<<dim3(Tc/128, Tc/64, Bc*Hc), 256, 0, stream>>>(
      qh, ql, kh, kl, probs);

  ucb_topk<<<dim3(Tc/4, Bc*Hc), 256, 0, stream>>>(
      ws, cnt, counter, ucb, probs, count_out, ctx);

  pv_gemm<<<dim3(Tc/64, Bc*Hc), 256, 0, stream>>>(
      probs, V, ctx, counter, ucb);

  split_plane<<<BTC/1024, 256, 0, stream>>>(ctx, ctxh, ctxl);
  splitT_w<<<dim3(24, 24), 256, 0, stream>>>(Wo, woth, wotl);

  out_mfma<<<dim3(Cch/128, (Bc*Tc)/64), 256, 0, stream>>>(
      ctxh, ctxl, woth, wotl, bo, out);
}